// Round 1
// baseline (1319.962 us; speedup 1.0000x reference)
//
#include <hip/hip_runtime.h>

// GraphSAGE 2-layer, N=100k, C 128->128->64, E=1.6M, fp32.
// Strategy: project-then-aggregate (linear commutes with mean-agg), CSR by dst.

constexpr int K = 128;  // inner dim of both GEMMs

// ---------------- CSR build ----------------

__global__ __launch_bounds__(256) void k_count(const int* __restrict__ dst,
                                               int* __restrict__ deg, int E, int n) {
  int e = blockIdx.x * 256 + threadIdx.x;
  if (e < E) {
    int d = dst[e];
    if ((unsigned)d < (unsigned)n) atomicAdd(&deg[d], 1);
  }
}

// single-block exclusive scan over N (~100k) elems; writes rowptr and cursor
__global__ __launch_bounds__(1024) void k_scan(const int* __restrict__ deg,
                                               int* __restrict__ rowptr,
                                               int* __restrict__ cursor, int n) {
  __shared__ int sums[1024];
  int t = threadIdx.x;
  int C = (n + 1023) >> 10;
  int b = t * C, e = min(b + C, n);
  int s = 0;
  for (int i = b; i < e; ++i) s += deg[i];
  sums[t] = s;
  __syncthreads();
  for (int off = 1; off < 1024; off <<= 1) {
    int v = (t >= off) ? sums[t - off] : 0;
    __syncthreads();
    sums[t] += v;
    __syncthreads();
  }
  int prefix = (t == 0) ? 0 : sums[t - 1];
  for (int i = b; i < e; ++i) {
    rowptr[i] = prefix;
    cursor[i] = prefix;
    prefix += deg[i];
  }
  if (t == 1023) rowptr[n] = sums[1023];
}

__global__ __launch_bounds__(256) void k_fill(const int* __restrict__ src,
                                              const int* __restrict__ dst,
                                              int* __restrict__ cursor,
                                              int* __restrict__ col, int E, int n) {
  int e = blockIdx.x * 256 + threadIdx.x;
  if (e < E) {
    int d = dst[e];
    if ((unsigned)d < (unsigned)n) {
      int s = src[e];
      s = min(max(s, 0), n - 1);  // safety clamp, no-op for valid input
      int pos = atomicAdd(&cursor[d], 1);
      col[pos] = s;
    }
  }
}

// ---------------- dual-output GEMM: [nrows,128] @ (Wa[128,COA], Wb[128,COB]) ----------------
// block = 256 threads, 16 rows/block; thread (r = tid&15, cg = tid>>4) computes
// CPT = (COA+COB)/16 contiguous output cols for one row. x-tile staged in LDS
// (pad 132 -> worst 2-way bank aliasing, free). W read from global (L1/L2-resident).

template <int COA, int COB>
__global__ __launch_bounds__(256) void k_gemm_dual(const float* __restrict__ X,
                                                   const float* __restrict__ Wa,
                                                   const float* __restrict__ Wb,
                                                   float* __restrict__ outA,
                                                   float* __restrict__ outB, int nrows) {
  constexpr int CTOT = COA + COB;
  constexpr int CPT = CTOT / 16;
  __shared__ float xs[16][132];
  int r = threadIdx.x & 15;
  int cg = threadIdx.x >> 4;
  long row0 = (long)blockIdx.x * 16;

  for (int i = threadIdx.x; i < 16 * 32; i += 256) {
    int rr = i >> 5, cc = (i & 31) << 2;
    long row = row0 + rr;
    float4 v = make_float4(0.f, 0.f, 0.f, 0.f);
    if (row < nrows) v = *(const float4*)(X + row * K + cc);
    xs[rr][cc] = v.x; xs[rr][cc + 1] = v.y; xs[rr][cc + 2] = v.z; xs[rr][cc + 3] = v.w;
  }
  __syncthreads();

  const float* Wp; float* outp;
  int cbase, stride;
  int c0 = cg * CPT;
  if (c0 < COA) { Wp = Wa; cbase = c0;       stride = COA; outp = outA; }
  else          { Wp = Wb; cbase = c0 - COA; stride = COB; outp = outB; }

  float acc[CPT];
#pragma unroll
  for (int j = 0; j < CPT; ++j) acc[j] = 0.f;

#pragma unroll 4
  for (int k = 0; k < K; ++k) {
    float xv = xs[r][k];
#pragma unroll
    for (int j = 0; j < CPT; j += 4) {
      float4 w = *(const float4*)(Wp + (long)k * stride + cbase + j);
      acc[j]     += xv * w.x;
      acc[j + 1] += xv * w.y;
      acc[j + 2] += xv * w.z;
      acc[j + 3] += xv * w.w;
    }
  }

  long row = row0 + r;
  if (row < nrows) {
#pragma unroll
    for (int j = 0; j < CPT; j += 4) {
      float4 v = make_float4(acc[j], acc[j + 1], acc[j + 2], acc[j + 3]);
      *(float4*)(outp + row * stride + cbase + j) = v;
    }
  }
}

// ---------------- aggregation: out[n] = mean_{s in nbrs(n)} Y[s] + XR[n] + bias (opt relu) ----
// one wave per node; CH=128 -> float2/lane, CH=64 -> float/lane.

template <int CH, bool RELU>
__global__ __launch_bounds__(256) void k_agg(const float* __restrict__ Y,
                                             const float* __restrict__ XR,
                                             const float* __restrict__ bias,
                                             const int* __restrict__ rowptr,
                                             const int* __restrict__ col,
                                             float* __restrict__ out, int nnodes) {
  int wave = threadIdx.x >> 6, lane = threadIdx.x & 63;
  int n = blockIdx.x * 4 + wave;
  if (n >= nnodes) return;
  int beg = rowptr[n], end = rowptr[n + 1];
  float inv = 1.f / (float)max(end - beg, 1);

  if constexpr (CH == 128) {
    float ax0 = 0.f, ay0 = 0.f, ax1 = 0.f, ay1 = 0.f;
    int j = beg;
    for (; j + 1 < end; j += 2) {
      long s0 = col[j], s1 = col[j + 1];
      float2 v0 = *(const float2*)(Y + s0 * 128 + lane * 2);
      float2 v1 = *(const float2*)(Y + s1 * 128 + lane * 2);
      ax0 += v0.x; ay0 += v0.y;
      ax1 += v1.x; ay1 += v1.y;
    }
    if (j < end) {
      long s = col[j];
      float2 v = *(const float2*)(Y + s * 128 + lane * 2);
      ax0 += v.x; ay0 += v.y;
    }
    float r0 = (ax0 + ax1) * inv + XR[(long)n * 128 + lane * 2]     + bias[lane * 2];
    float r1 = (ay0 + ay1) * inv + XR[(long)n * 128 + lane * 2 + 1] + bias[lane * 2 + 1];
    if (RELU) { r0 = fmaxf(r0, 0.f); r1 = fmaxf(r1, 0.f); }
    *(float2*)(out + (long)n * 128 + lane * 2) = make_float2(r0, r1);
  } else {
    float a0 = 0.f, a1 = 0.f;
    int j = beg;
    for (; j + 1 < end; j += 2) {
      long s0 = col[j], s1 = col[j + 1];
      a0 += Y[s0 * CH + lane];
      a1 += Y[s1 * CH + lane];
    }
    if (j < end) a0 += Y[(long)col[j] * CH + lane];
    float r0 = (a0 + a1) * inv + XR[(long)n * CH + lane] + bias[lane];
    if (RELU) r0 = fmaxf(r0, 0.f);
    out[(long)n * CH + lane] = r0;
  }
}

// ---------------- launch ----------------

extern "C" void kernel_launch(void* const* d_in, const int* in_sizes, int n_in,
                              void* d_out, int out_size, void* d_ws, size_t ws_size,
                              hipStream_t stream) {
  const float* x   = (const float*)d_in[0];
  const int*   ei  = (const int*)d_in[1];
  const float* W1l = (const float*)d_in[2];
  const float* W1r = (const float*)d_in[3];
  const float* b1  = (const float*)d_in[4];
  const float* W2l = (const float*)d_in[5];
  const float* W2r = (const float*)d_in[6];
  const float* b2  = (const float*)d_in[7];
  float* out = (float*)d_out;

  int N = in_sizes[0] / K;   // 100000
  int E = in_sizes[1] / 2;   // 1600000
  const int* src = ei;
  const int* dst = ei + E;

  char* ws = (char*)d_ws;
  size_t off = 0;
  auto alloc = [&](size_t bytes) {
    void* p = ws + off;
    off = (off + bytes + 255) & ~(size_t)255;
    return p;
  };
  int*   deg    = (int*)alloc((size_t)N * 4);
  int*   rowptr = (int*)alloc(((size_t)N + 1) * 4);
  int*   cursor = (int*)alloc((size_t)N * 4);
  int*   col    = (int*)alloc((size_t)E * 4);
  float* y1     = (float*)alloc((size_t)N * 128 * 4);
  float* xr     = (float*)alloc((size_t)N * 128 * 4);
  float* h      = (float*)alloc((size_t)N * 128 * 4);
  float* y2 = y1;  // layer-1 buffers dead after k_agg<128>; reuse
  float* hr = xr;

  hipMemsetAsync(deg, 0, (size_t)N * 4, stream);
  k_count<<<(E + 255) / 256, 256, 0, stream>>>(dst, deg, E, N);
  k_scan<<<1, 1024, 0, stream>>>(deg, rowptr, cursor, N);
  k_fill<<<(E + 255) / 256, 256, 0, stream>>>(src, dst, cursor, col, E, N);

  // layer 1: y1 = x@W1l, xr = x@W1r; h = relu(mean(y1) + xr + b1)
  k_gemm_dual<128, 128><<<(N + 15) / 16, 256, 0, stream>>>(x, W1l, W1r, y1, xr, N);
  k_agg<128, true><<<(N + 3) / 4, 256, 0, stream>>>(y1, xr, b1, rowptr, col, h, N);

  // layer 2: y2 = h@W2l, hr = h@W2r; out = mean(y2) + hr + b2
  k_gemm_dual<64, 64><<<(N + 15) / 16, 256, 0, stream>>>(h, W2l, W2r, y2, hr, N);
  k_agg<64, false><<<(N + 3) / 4, 256, 0, stream>>>(y2, hr, b2, rowptr, col, out, N);
}

// Round 2
// 801.675 us; speedup vs baseline: 1.6465x; 1.6465x over previous
//
#include <hip/hip_runtime.h>

// GraphSAGE 2-layer, N=100k, C 128->128->64, E=1.6M, fp32 in/out.
// R2: bf16-MFMA GEMMs (fp32 accum). Project-then-aggregate, CSR by dst.

constexpr int K = 128;  // inner dim of both GEMMs

typedef __bf16 bf16x4 __attribute__((ext_vector_type(4)));
typedef __bf16 bf16x8 __attribute__((ext_vector_type(8)));
typedef float f32x4 __attribute__((ext_vector_type(4)));

// ---------------- CSR build ----------------

__global__ __launch_bounds__(256) void k_count(const int* __restrict__ dst,
                                               int* __restrict__ deg, int E, int n) {
  int e = blockIdx.x * 256 + threadIdx.x;
  if (e < E) {
    int d = dst[e];
    if ((unsigned)d < (unsigned)n) atomicAdd(&deg[d], 1);
  }
}

__global__ __launch_bounds__(1024) void k_scan(const int* __restrict__ deg,
                                               int* __restrict__ rowptr,
                                               int* __restrict__ cursor, int n) {
  __shared__ int sums[1024];
  int t = threadIdx.x;
  int C = (n + 1023) >> 10;
  int b = t * C, e = min(b + C, n);
  int s = 0;
  for (int i = b; i < e; ++i) s += deg[i];
  sums[t] = s;
  __syncthreads();
  for (int off = 1; off < 1024; off <<= 1) {
    int v = (t >= off) ? sums[t - off] : 0;
    __syncthreads();
    sums[t] += v;
    __syncthreads();
  }
  int prefix = (t == 0) ? 0 : sums[t - 1];
  for (int i = b; i < e; ++i) {
    rowptr[i] = prefix;
    cursor[i] = prefix;
    prefix += deg[i];
  }
  if (t == 1023) rowptr[n] = sums[1023];
}

__global__ __launch_bounds__(256) void k_fill(const int* __restrict__ src,
                                              const int* __restrict__ dst,
                                              int* __restrict__ cursor,
                                              int* __restrict__ col, int E, int n) {
  int e = blockIdx.x * 256 + threadIdx.x;
  if (e < E) {
    int d = dst[e];
    if ((unsigned)d < (unsigned)n) {
      int s = src[e];
      s = min(max(s, 0), n - 1);
      int pos = atomicAdd(&cursor[d], 1);
      col[pos] = s;
    }
  }
}

// ---------------- bf16 MFMA GEMM ----------------
// out[64 rows x COLS] = X[64 x 128] @ W[128 x COLS], one W matrix per blockIdx.y.
// Block 256 thr = 4 waves; wave tile 32 x COLS/2. LDS: A [64][136] bf16 row-major,
// B transposed Bt[c][k] [COLS][136] bf16 (pad 136 keeps ds_read_b128 16B-aligned,
// 2-way bank aliasing only = free). Layouts per guide: A[m=lane&15][k=quad*8+j],
// B[n=lane&15][k=quad*8+j], C/D col=lane&15 row=quad*4+reg (m89/m91-verified).

template <int COLS>
__global__ __launch_bounds__(256) void k_gemm_mfma(const float* __restrict__ X,
                                                   const float* __restrict__ Wa,
                                                   const float* __restrict__ Wb,
                                                   float* __restrict__ outA,
                                                   float* __restrict__ outB, int nrows) {
  constexpr int LD = 136;             // padded bf16 leading dim
  constexpr int MT_N = COLS / 32;     // 16x16 col-tiles per wave
  __shared__ __bf16 sh[(64 + COLS) * LD];
  __bf16* As = sh;
  __bf16* Bt = sh + 64 * LD;

  const float* W = (blockIdx.y == 0) ? Wa : Wb;
  float* outp = (blockIdx.y == 0) ? outA : outB;

  int tid = threadIdx.x;
  long row0 = (long)blockIdx.x * 64;

  // stage A: 64x128 floats -> bf16, 2048 float4 / 256 thr = 8 iters
#pragma unroll
  for (int it = 0; it < 8; ++it) {
    int i = tid + it * 256;
    int r = i >> 5, c4 = (i & 31) << 2;
    long row = row0 + r;
    float4 v = make_float4(0.f, 0.f, 0.f, 0.f);
    if (row < nrows) v = *(const float4*)(X + row * K + c4);
    bf16x4 b;
    b[0] = (__bf16)v.x; b[1] = (__bf16)v.y; b[2] = (__bf16)v.z; b[3] = (__bf16)v.w;
    *(bf16x4*)&As[r * LD + c4] = b;
  }
  // stage B transposed: K x COLS floats -> Bt[c][k]
  constexpr int C4 = COLS / 4;  // float4s per k-row
#pragma unroll
  for (int it = 0; it < (32 * COLS) / 256; ++it) {
    int i = tid + it * 256;
    int k = i / C4, c = (i % C4) << 2;
    float4 v = *(const float4*)(W + (long)k * COLS + c);
    Bt[(c + 0) * LD + k] = (__bf16)v.x;
    Bt[(c + 1) * LD + k] = (__bf16)v.y;
    Bt[(c + 2) * LD + k] = (__bf16)v.z;
    Bt[(c + 3) * LD + k] = (__bf16)v.w;
  }
  __syncthreads();

  int w = tid >> 6, lane = tid & 63;
  int m = lane & 15, quad = lane >> 4;
  int wrow = (w >> 1) * 32;
  int wcol = (w & 1) * (COLS / 2);

  f32x4 acc[2][MT_N];
#pragma unroll
  for (int mi = 0; mi < 2; ++mi)
#pragma unroll
    for (int ni = 0; ni < MT_N; ++ni) acc[mi][ni] = (f32x4){0.f, 0.f, 0.f, 0.f};

#pragma unroll
  for (int kc = 0; kc < 4; ++kc) {
    int ko = kc * 32 + quad * 8;
    bf16x8 af[2];
#pragma unroll
    for (int mi = 0; mi < 2; ++mi)
      af[mi] = *(const bf16x8*)&As[(wrow + mi * 16 + m) * LD + ko];
    bf16x8 bfr[MT_N];
#pragma unroll
    for (int ni = 0; ni < MT_N; ++ni)
      bfr[ni] = *(const bf16x8*)&Bt[(wcol + ni * 16 + m) * LD + ko];
#pragma unroll
    for (int mi = 0; mi < 2; ++mi)
#pragma unroll
      for (int ni = 0; ni < MT_N; ++ni)
        acc[mi][ni] = __builtin_amdgcn_mfma_f32_16x16x32_bf16(af[mi], bfr[ni], acc[mi][ni], 0, 0, 0);
  }

#pragma unroll
  for (int mi = 0; mi < 2; ++mi) {
#pragma unroll
    for (int r = 0; r < 4; ++r) {
      long grow = row0 + wrow + mi * 16 + quad * 4 + r;
      if (grow < nrows) {
#pragma unroll
        for (int ni = 0; ni < MT_N; ++ni)
          outp[grow * COLS + wcol + ni * 16 + m] = acc[mi][ni][r];
      }
    }
  }
}

// ---------------- aggregation ----------------

template <int CH, bool RELU>
__global__ __launch_bounds__(256) void k_agg(const float* __restrict__ Y,
                                             const float* __restrict__ XR,
                                             const float* __restrict__ bias,
                                             const int* __restrict__ rowptr,
                                             const int* __restrict__ col,
                                             float* __restrict__ out, int nnodes) {
  int wave = threadIdx.x >> 6, lane = threadIdx.x & 63;
  int n = blockIdx.x * 4 + wave;
  if (n >= nnodes) return;
  int beg = rowptr[n], end = rowptr[n + 1];
  float inv = 1.f / (float)max(end - beg, 1);

  if constexpr (CH == 128) {
    float ax0 = 0.f, ay0 = 0.f, ax1 = 0.f, ay1 = 0.f;
    int j = beg;
    for (; j + 1 < end; j += 2) {
      long s0 = col[j], s1 = col[j + 1];
      float2 v0 = *(const float2*)(Y + s0 * 128 + lane * 2);
      float2 v1 = *(const float2*)(Y + s1 * 128 + lane * 2);
      ax0 += v0.x; ay0 += v0.y;
      ax1 += v1.x; ay1 += v1.y;
    }
    if (j < end) {
      long s = col[j];
      float2 v = *(const float2*)(Y + s * 128 + lane * 2);
      ax0 += v.x; ay0 += v.y;
    }
    float r0 = (ax0 + ax1) * inv + XR[(long)n * 128 + lane * 2]     + bias[lane * 2];
    float r1 = (ay0 + ay1) * inv + XR[(long)n * 128 + lane * 2 + 1] + bias[lane * 2 + 1];
    if (RELU) { r0 = fmaxf(r0, 0.f); r1 = fmaxf(r1, 0.f); }
    *(float2*)(out + (long)n * 128 + lane * 2) = make_float2(r0, r1);
  } else {
    float a0 = 0.f, a1 = 0.f;
    int j = beg;
    for (; j + 1 < end; j += 2) {
      long s0 = col[j], s1 = col[j + 1];
      a0 += Y[s0 * CH + lane];
      a1 += Y[s1 * CH + lane];
    }
    if (j < end) a0 += Y[(long)col[j] * CH + lane];
    float r0 = (a0 + a1) * inv + XR[(long)n * CH + lane] + bias[lane];
    if (RELU) r0 = fmaxf(r0, 0.f);
    out[(long)n * CH + lane] = r0;
  }
}

// ---------------- launch ----------------

extern "C" void kernel_launch(void* const* d_in, const int* in_sizes, int n_in,
                              void* d_out, int out_size, void* d_ws, size_t ws_size,
                              hipStream_t stream) {
  const float* x   = (const float*)d_in[0];
  const int*   ei  = (const int*)d_in[1];
  const float* W1l = (const float*)d_in[2];
  const float* W1r = (const float*)d_in[3];
  const float* b1  = (const float*)d_in[4];
  const float* W2l = (const float*)d_in[5];
  const float* W2r = (const float*)d_in[6];
  const float* b2  = (const float*)d_in[7];
  float* out = (float*)d_out;

  int N = in_sizes[0] / K;   // 100000
  int E = in_sizes[1] / 2;   // 1600000
  const int* src = ei;
  const int* dst = ei + E;

  char* ws = (char*)d_ws;
  size_t off = 0;
  auto alloc = [&](size_t bytes) {
    void* p = ws + off;
    off = (off + bytes + 255) & ~(size_t)255;
    return p;
  };
  int*   deg    = (int*)alloc((size_t)N * 4);
  int*   rowptr = (int*)alloc(((size_t)N + 1) * 4);
  int*   cursor = (int*)alloc((size_t)N * 4);
  int*   col    = (int*)alloc((size_t)E * 4);
  float* y1     = (float*)alloc((size_t)N * 128 * 4);
  float* xr     = (float*)alloc((size_t)N * 128 * 4);
  float* h      = (float*)alloc((size_t)N * 128 * 4);
  float* y2 = y1;  // layer-1 buffers dead after k_agg<128>; reuse
  float* hr = xr;

  hipMemsetAsync(deg, 0, (size_t)N * 4, stream);
  k_count<<<(E + 255) / 256, 256, 0, stream>>>(dst, deg, E, N);
  k_scan<<<1, 1024, 0, stream>>>(deg, rowptr, cursor, N);
  k_fill<<<(E + 255) / 256, 256, 0, stream>>>(src, dst, cursor, col, E, N);

  int gx = (N + 63) / 64;
  // layer 1: y1 = x@W1l, xr = x@W1r; h = relu(mean(y1) + xr + b1)
  k_gemm_mfma<128><<<dim3(gx, 2), 256, 0, stream>>>(x, W1l, W1r, y1, xr, N);
  k_agg<128, true><<<(N + 3) / 4, 256, 0, stream>>>(y1, xr, b1, rowptr, col, h, N);

  // layer 2: y2 = h@W2l, hr = h@W2r; out = mean(y2) + hr + b2
  k_gemm_mfma<64><<<dim3(gx, 2), 256, 0, stream>>>(h, W2l, W2r, y2, hr, N);
  k_agg<64, false><<<(N + 3) / 4, 256, 0, stream>>>(y2, hr, b2, rowptr, col, out, N);
}

// Round 3
// 630.413 us; speedup vs baseline: 2.0938x; 1.2717x over previous
//
#include <hip/hip_runtime.h>

// GraphSAGE 2-layer, N=100k, C 128->128->64, E=1.6M, fp32 in/out.
// R3: hierarchical CSR scan (was 229us single-block). bf16-MFMA GEMMs.

constexpr int K = 128;  // inner dim of both GEMMs

typedef __bf16 bf16x4 __attribute__((ext_vector_type(4)));
typedef __bf16 bf16x8 __attribute__((ext_vector_type(8)));
typedef float f32x4 __attribute__((ext_vector_type(4)));

// ---------------- CSR build ----------------

__global__ __launch_bounds__(256) void k_count(const int* __restrict__ dst,
                                               int* __restrict__ deg, int E, int n) {
  int e = blockIdx.x * 256 + threadIdx.x;
  if (e < E) {
    int d = dst[e];
    if ((unsigned)d < (unsigned)n) atomicAdd(&deg[d], 1);
  }
}

// hierarchical exclusive scan: 2048 elems per block (256 thr x 8)
__global__ __launch_bounds__(256) void k_scan_partial(const int* __restrict__ deg,
                                                      int* __restrict__ partial, int n) {
  __shared__ int red[256];
  int t = threadIdx.x;
  int base = blockIdx.x * 2048 + t * 8;
  int s = 0;
  if (base + 8 <= n) {
    int4 a = *(const int4*)(deg + base);
    int4 b = *(const int4*)(deg + base + 4);
    s = a.x + a.y + a.z + a.w + b.x + b.y + b.z + b.w;
  } else {
    for (int i = base; i < n; ++i) s += deg[i];
  }
  red[t] = s;
  __syncthreads();
  for (int off = 128; off > 0; off >>= 1) {
    if (t < off) red[t] += red[t + off];
    __syncthreads();
  }
  if (t == 0) partial[blockIdx.x] = red[0];
}

__global__ __launch_bounds__(256) void k_scan_top(int* __restrict__ partial, int nb) {
  __shared__ int sh[256];
  int t = threadIdx.x;
  sh[t] = (t < nb) ? partial[t] : 0;
  __syncthreads();
  for (int off = 1; off < 256; off <<= 1) {
    int u = (t >= off) ? sh[t - off] : 0;
    __syncthreads();
    sh[t] += u;
    __syncthreads();
  }
  if (t < nb) partial[t] = (t == 0) ? 0 : sh[t - 1];  // exclusive
}

__global__ __launch_bounds__(256) void k_scan_apply(const int* __restrict__ deg,
                                                    const int* __restrict__ partial,
                                                    int* __restrict__ rowptr,
                                                    int* __restrict__ cursor, int n) {
  __shared__ int red[256];
  int t = threadIdx.x;
  int base = blockIdx.x * 2048 + t * 8;
  int loc[8], s = 0;
#pragma unroll
  for (int i = 0; i < 8; ++i) {
    int idx = base + i;
    int v = (idx < n) ? deg[idx] : 0;
    loc[i] = s;
    s += v;
  }
  red[t] = s;
  __syncthreads();
  for (int off = 1; off < 256; off <<= 1) {
    int u = (t >= off) ? red[t - off] : 0;
    __syncthreads();
    red[t] += u;
    __syncthreads();
  }
  int texcl = (t == 0) ? 0 : red[t - 1];
  int bofs = partial[blockIdx.x];
#pragma unroll
  for (int i = 0; i < 8; ++i) {
    int idx = base + i;
    if (idx < n) {
      int p = bofs + texcl + loc[i];
      rowptr[idx] = p;
      cursor[idx] = p;
    }
  }
  if (blockIdx.x == gridDim.x - 1 && t == 255) rowptr[n] = bofs + red[255];
}

__global__ __launch_bounds__(256) void k_fill(const int* __restrict__ src,
                                              const int* __restrict__ dst,
                                              int* __restrict__ cursor,
                                              int* __restrict__ col, int E, int n) {
  int e = blockIdx.x * 256 + threadIdx.x;
  if (e < E) {
    int d = dst[e];
    if ((unsigned)d < (unsigned)n) {
      int s = src[e];
      s = min(max(s, 0), n - 1);
      int pos = atomicAdd(&cursor[d], 1);
      col[pos] = s;
    }
  }
}

// ---------------- bf16 MFMA GEMM ----------------
// out[64 rows x COLS] = X[64 x 128] @ W[128 x COLS], one W matrix per blockIdx.y.

template <int COLS>
__global__ __launch_bounds__(256) void k_gemm_mfma(const float* __restrict__ X,
                                                   const float* __restrict__ Wa,
                                                   const float* __restrict__ Wb,
                                                   float* __restrict__ outA,
                                                   float* __restrict__ outB, int nrows) {
  constexpr int LD = 136;
  constexpr int MT_N = COLS / 32;
  __shared__ __bf16 sh[(64 + COLS) * LD];
  __bf16* As = sh;
  __bf16* Bt = sh + 64 * LD;

  const float* W = (blockIdx.y == 0) ? Wa : Wb;
  float* outp = (blockIdx.y == 0) ? outA : outB;

  int tid = threadIdx.x;
  long row0 = (long)blockIdx.x * 64;

#pragma unroll
  for (int it = 0; it < 8; ++it) {
    int i = tid + it * 256;
    int r = i >> 5, c4 = (i & 31) << 2;
    long row = row0 + r;
    float4 v = make_float4(0.f, 0.f, 0.f, 0.f);
    if (row < nrows) v = *(const float4*)(X + row * K + c4);
    bf16x4 b;
    b[0] = (__bf16)v.x; b[1] = (__bf16)v.y; b[2] = (__bf16)v.z; b[3] = (__bf16)v.w;
    *(bf16x4*)&As[r * LD + c4] = b;
  }
  constexpr int C4 = COLS / 4;
#pragma unroll
  for (int it = 0; it < (32 * COLS) / 256; ++it) {
    int i = tid + it * 256;
    int k = i / C4, c = (i % C4) << 2;
    float4 v = *(const float4*)(W + (long)k * COLS + c);
    Bt[(c + 0) * LD + k] = (__bf16)v.x;
    Bt[(c + 1) * LD + k] = (__bf16)v.y;
    Bt[(c + 2) * LD + k] = (__bf16)v.z;
    Bt[(c + 3) * LD + k] = (__bf16)v.w;
  }
  __syncthreads();

  int w = tid >> 6, lane = tid & 63;
  int m = lane & 15, quad = lane >> 4;
  int wrow = (w >> 1) * 32;
  int wcol = (w & 1) * (COLS / 2);

  f32x4 acc[2][MT_N];
#pragma unroll
  for (int mi = 0; mi < 2; ++mi)
#pragma unroll
    for (int ni = 0; ni < MT_N; ++ni) acc[mi][ni] = (f32x4){0.f, 0.f, 0.f, 0.f};

#pragma unroll
  for (int kc = 0; kc < 4; ++kc) {
    int ko = kc * 32 + quad * 8;
    bf16x8 af[2];
#pragma unroll
    for (int mi = 0; mi < 2; ++mi)
      af[mi] = *(const bf16x8*)&As[(wrow + mi * 16 + m) * LD + ko];
    bf16x8 bfr[MT_N];
#pragma unroll
    for (int ni = 0; ni < MT_N; ++ni)
      bfr[ni] = *(const bf16x8*)&Bt[(wcol + ni * 16 + m) * LD + ko];
#pragma unroll
    for (int mi = 0; mi < 2; ++mi)
#pragma unroll
      for (int ni = 0; ni < MT_N; ++ni)
        acc[mi][ni] = __builtin_amdgcn_mfma_f32_16x16x32_bf16(af[mi], bfr[ni], acc[mi][ni], 0, 0, 0);
  }

#pragma unroll
  for (int mi = 0; mi < 2; ++mi) {
#pragma unroll
    for (int r = 0; r < 4; ++r) {
      long grow = row0 + wrow + mi * 16 + quad * 4 + r;
      if (grow < nrows) {
#pragma unroll
        for (int ni = 0; ni < MT_N; ++ni)
          outp[grow * COLS + wcol + ni * 16 + m] = acc[mi][ni][r];
      }
    }
  }
}

// ---------------- aggregation ----------------

template <int CH, bool RELU>
__global__ __launch_bounds__(256) void k_agg(const float* __restrict__ Y,
                                             const float* __restrict__ XR,
                                             const float* __restrict__ bias,
                                             const int* __restrict__ rowptr,
                                             const int* __restrict__ col,
                                             float* __restrict__ out, int nnodes) {
  int wave = threadIdx.x >> 6, lane = threadIdx.x & 63;
  int n = blockIdx.x * 4 + wave;
  if (n >= nnodes) return;
  int beg = rowptr[n], end = rowptr[n + 1];
  float inv = 1.f / (float)max(end - beg, 1);

  if constexpr (CH == 128) {
    float ax0 = 0.f, ay0 = 0.f, ax1 = 0.f, ay1 = 0.f;
    int j = beg;
    for (; j + 1 < end; j += 2) {
      long s0 = col[j], s1 = col[j + 1];
      float2 v0 = *(const float2*)(Y + s0 * 128 + lane * 2);
      float2 v1 = *(const float2*)(Y + s1 * 128 + lane * 2);
      ax0 += v0.x; ay0 += v0.y;
      ax1 += v1.x; ay1 += v1.y;
    }
    if (j < end) {
      long s = col[j];
      float2 v = *(const float2*)(Y + s * 128 + lane * 2);
      ax0 += v.x; ay0 += v.y;
    }
    float r0 = (ax0 + ax1) * inv + XR[(long)n * 128 + lane * 2]     + bias[lane * 2];
    float r1 = (ay0 + ay1) * inv + XR[(long)n * 128 + lane * 2 + 1] + bias[lane * 2 + 1];
    if (RELU) { r0 = fmaxf(r0, 0.f); r1 = fmaxf(r1, 0.f); }
    *(float2*)(out + (long)n * 128 + lane * 2) = make_float2(r0, r1);
  } else {
    float a0 = 0.f, a1 = 0.f;
    int j = beg;
    for (; j + 1 < end; j += 2) {
      long s0 = col[j], s1 = col[j + 1];
      a0 += Y[s0 * CH + lane];
      a1 += Y[s1 * CH + lane];
    }
    if (j < end) a0 += Y[(long)col[j] * CH + lane];
    float r0 = (a0 + a1) * inv + XR[(long)n * CH + lane] + bias[lane];
    if (RELU) r0 = fmaxf(r0, 0.f);
    out[(long)n * CH + lane] = r0;
  }
}

// ---------------- launch ----------------

extern "C" void kernel_launch(void* const* d_in, const int* in_sizes, int n_in,
                              void* d_out, int out_size, void* d_ws, size_t ws_size,
                              hipStream_t stream) {
  const float* x   = (const float*)d_in[0];
  const int*   ei  = (const int*)d_in[1];
  const float* W1l = (const float*)d_in[2];
  const float* W1r = (const float*)d_in[3];
  const float* b1  = (const float*)d_in[4];
  const float* W2l = (const float*)d_in[5];
  const float* W2r = (const float*)d_in[6];
  const float* b2  = (const float*)d_in[7];
  float* out = (float*)d_out;

  int N = in_sizes[0] / K;   // 100000
  int E = in_sizes[1] / 2;   // 1600000
  const int* src = ei;
  const int* dst = ei + E;

  char* ws = (char*)d_ws;
  size_t off = 0;
  auto alloc = [&](size_t bytes) {
    void* p = ws + off;
    off = (off + bytes + 255) & ~(size_t)255;
    return p;
  };
  int*   deg     = (int*)alloc((size_t)N * 4);
  int*   rowptr  = (int*)alloc(((size_t)N + 1) * 4);
  int*   cursor  = (int*)alloc((size_t)N * 4);
  int*   partial = (int*)alloc(256 * 4);
  int*   col     = (int*)alloc((size_t)E * 4);
  float* y1      = (float*)alloc((size_t)N * 128 * 4);
  float* xr      = (float*)alloc((size_t)N * 128 * 4);
  float* h       = (float*)alloc((size_t)N * 128 * 4);
  float* y2 = y1;  // layer-1 buffers dead after k_agg<128>; reuse
  float* hr = xr;

  int nb = (N + 2047) / 2048;  // 49 scan blocks

  hipMemsetAsync(deg, 0, (size_t)N * 4, stream);
  k_count<<<(E + 255) / 256, 256, 0, stream>>>(dst, deg, E, N);
  k_scan_partial<<<nb, 256, 0, stream>>>(deg, partial, N);
  k_scan_top<<<1, 256, 0, stream>>>(partial, nb);
  k_scan_apply<<<nb, 256, 0, stream>>>(deg, partial, rowptr, cursor, N);
  k_fill<<<(E + 255) / 256, 256, 0, stream>>>(src, dst, cursor, col, E, N);

  int gx = (N + 63) / 64;
  // layer 1: y1 = x@W1l, xr = x@W1r; h = relu(mean(y1) + xr + b1)
  k_gemm_mfma<128><<<dim3(gx, 2), 256, 0, stream>>>(x, W1l, W1r, y1, xr, N);
  k_agg<128, true><<<(N + 3) / 4, 256, 0, stream>>>(y1, xr, b1, rowptr, col, h, N);

  // layer 2: y2 = h@W2l, hr = h@W2r; out = mean(y2) + hr + b2
  k_gemm_mfma<64><<<dim3(gx, 2), 256, 0, stream>>>(h, W2l, W2r, y2, hr, N);
  k_agg<64, false><<<(N + 3) / 4, 256, 0, stream>>>(y2, hr, b2, rowptr, col, out, N);
}

// Round 4
// 515.879 us; speedup vs baseline: 2.5587x; 1.2220x over previous
//
#include <hip/hip_runtime.h>
#include <type_traits>

// GraphSAGE 2-layer, N=100k, C 128->128->64, E=1.6M, fp32 in/out.
// R4: bf16 intermediates (halve gather+write traffic), MLP-unrolled aggs.

constexpr int K = 128;

typedef __bf16 bf16x2 __attribute__((ext_vector_type(2)));
typedef __bf16 bf16x4 __attribute__((ext_vector_type(4)));
typedef __bf16 bf16x8 __attribute__((ext_vector_type(8)));
typedef float f32x4 __attribute__((ext_vector_type(4)));

// ---------------- CSR build ----------------

__global__ __launch_bounds__(256) void k_count(const int* __restrict__ dst,
                                               int* __restrict__ deg, int E, int n) {
  int e = blockIdx.x * 256 + threadIdx.x;
  if (e < E) {
    int d = dst[e];
    if ((unsigned)d < (unsigned)n) atomicAdd(&deg[d], 1);
  }
}

__global__ __launch_bounds__(256) void k_scan_partial(const int* __restrict__ deg,
                                                      int* __restrict__ partial, int n) {
  __shared__ int red[256];
  int t = threadIdx.x;
  int base = blockIdx.x * 2048 + t * 8;
  int s = 0;
  if (base + 8 <= n) {
    int4 a = *(const int4*)(deg + base);
    int4 b = *(const int4*)(deg + base + 4);
    s = a.x + a.y + a.z + a.w + b.x + b.y + b.z + b.w;
  } else {
    for (int i = base; i < n; ++i) s += deg[i];
  }
  red[t] = s;
  __syncthreads();
  for (int off = 128; off > 0; off >>= 1) {
    if (t < off) red[t] += red[t + off];
    __syncthreads();
  }
  if (t == 0) partial[blockIdx.x] = red[0];
}

__global__ __launch_bounds__(256) void k_scan_top(int* __restrict__ partial, int nb) {
  __shared__ int sh[256];
  int t = threadIdx.x;
  sh[t] = (t < nb) ? partial[t] : 0;
  __syncthreads();
  for (int off = 1; off < 256; off <<= 1) {
    int u = (t >= off) ? sh[t - off] : 0;
    __syncthreads();
    sh[t] += u;
    __syncthreads();
  }
  if (t < nb) partial[t] = (t == 0) ? 0 : sh[t - 1];
}

__global__ __launch_bounds__(256) void k_scan_apply(const int* __restrict__ deg,
                                                    const int* __restrict__ partial,
                                                    int* __restrict__ rowptr,
                                                    int* __restrict__ cursor, int n) {
  __shared__ int red[256];
  int t = threadIdx.x;
  int base = blockIdx.x * 2048 + t * 8;
  int loc[8], s = 0;
#pragma unroll
  for (int i = 0; i < 8; ++i) {
    int idx = base + i;
    int v = (idx < n) ? deg[idx] : 0;
    loc[i] = s;
    s += v;
  }
  red[t] = s;
  __syncthreads();
  for (int off = 1; off < 256; off <<= 1) {
    int u = (t >= off) ? red[t - off] : 0;
    __syncthreads();
    red[t] += u;
    __syncthreads();
  }
  int texcl = (t == 0) ? 0 : red[t - 1];
  int bofs = partial[blockIdx.x];
#pragma unroll
  for (int i = 0; i < 8; ++i) {
    int idx = base + i;
    if (idx < n) {
      int p = bofs + texcl + loc[i];
      rowptr[idx] = p;
      cursor[idx] = p;
    }
  }
  if (blockIdx.x == gridDim.x - 1 && t == 255) rowptr[n] = bofs + red[255];
}

__global__ __launch_bounds__(256) void k_fill(const int* __restrict__ src,
                                              const int* __restrict__ dst,
                                              int* __restrict__ cursor,
                                              int* __restrict__ col, int E, int n) {
  int e = blockIdx.x * 256 + threadIdx.x;
  if (e < E) {
    int d = dst[e];
    if ((unsigned)d < (unsigned)n) {
      int s = src[e];
      s = min(max(s, 0), n - 1);
      int pos = atomicAdd(&cursor[d], 1);
      col[pos] = s;
    }
  }
}

// ---------------- bf16 MFMA GEMM ----------------
// out[64 x COLS] = X[64 x 128] @ W[128 x COLS]; blockIdx.y picks (Wa,outA)/(Wb,outB).
// TIN: float (layer 1 input x) or __bf16 (layer 2 input h). Output bf16.

template <int COLS, typename TIN>
__global__ __launch_bounds__(256) void k_gemm_mfma(const TIN* __restrict__ X,
                                                   const float* __restrict__ Wa,
                                                   const float* __restrict__ Wb,
                                                   __bf16* __restrict__ outA,
                                                   __bf16* __restrict__ outB, int nrows) {
  constexpr int LD = 136;
  constexpr int MT_N = COLS / 32;
  __shared__ __bf16 sh[(64 + COLS) * LD];
  __bf16* As = sh;
  __bf16* Bt = sh + 64 * LD;

  const float* W = (blockIdx.y == 0) ? Wa : Wb;
  __bf16* outp = (blockIdx.y == 0) ? outA : outB;

  int tid = threadIdx.x;
  long row0 = (long)blockIdx.x * 64;

  if constexpr (std::is_same_v<TIN, float>) {
#pragma unroll
    for (int it = 0; it < 8; ++it) {
      int i = tid + it * 256;
      int r = i >> 5, c4 = (i & 31) << 2;
      long row = row0 + r;
      float4 v = make_float4(0.f, 0.f, 0.f, 0.f);
      if (row < nrows) v = *(const float4*)(X + row * K + c4);
      bf16x4 b;
      b[0] = (__bf16)v.x; b[1] = (__bf16)v.y; b[2] = (__bf16)v.z; b[3] = (__bf16)v.w;
      *(bf16x4*)&As[r * LD + c4] = b;
    }
  } else {
#pragma unroll
    for (int it = 0; it < 4; ++it) {
      int i = tid + it * 256;
      int r = i >> 4, c8 = (i & 15) << 3;
      long row = row0 + r;
      bf16x8 v = {};
      if (row < nrows) v = *(const bf16x8*)(X + row * K + c8);
      *(bf16x8*)&As[r * LD + c8] = v;
    }
  }
  constexpr int C4 = COLS / 4;
#pragma unroll
  for (int it = 0; it < (32 * COLS) / 256; ++it) {
    int i = tid + it * 256;
    int k = i / C4, c = (i % C4) << 2;
    float4 v = *(const float4*)(W + (long)k * COLS + c);
    Bt[(c + 0) * LD + k] = (__bf16)v.x;
    Bt[(c + 1) * LD + k] = (__bf16)v.y;
    Bt[(c + 2) * LD + k] = (__bf16)v.z;
    Bt[(c + 3) * LD + k] = (__bf16)v.w;
  }
  __syncthreads();

  int w = tid >> 6, lane = tid & 63;
  int m = lane & 15, quad = lane >> 4;
  int wrow = (w >> 1) * 32;
  int wcol = (w & 1) * (COLS / 2);

  f32x4 acc[2][MT_N];
#pragma unroll
  for (int mi = 0; mi < 2; ++mi)
#pragma unroll
    for (int ni = 0; ni < MT_N; ++ni) acc[mi][ni] = (f32x4){0.f, 0.f, 0.f, 0.f};

#pragma unroll
  for (int kc = 0; kc < 4; ++kc) {
    int ko = kc * 32 + quad * 8;
    bf16x8 af[2];
#pragma unroll
    for (int mi = 0; mi < 2; ++mi)
      af[mi] = *(const bf16x8*)&As[(wrow + mi * 16 + m) * LD + ko];
    bf16x8 bfr[MT_N];
#pragma unroll
    for (int ni = 0; ni < MT_N; ++ni)
      bfr[ni] = *(const bf16x8*)&Bt[(wcol + ni * 16 + m) * LD + ko];
#pragma unroll
    for (int mi = 0; mi < 2; ++mi)
#pragma unroll
      for (int ni = 0; ni < MT_N; ++ni)
        acc[mi][ni] = __builtin_amdgcn_mfma_f32_16x16x32_bf16(af[mi], bfr[ni], acc[mi][ni], 0, 0, 0);
  }

#pragma unroll
  for (int mi = 0; mi < 2; ++mi) {
#pragma unroll
    for (int r = 0; r < 4; ++r) {
      long grow = row0 + wrow + mi * 16 + quad * 4 + r;
      if (grow < nrows) {
#pragma unroll
        for (int ni = 0; ni < MT_N; ++ni)
          outp[grow * COLS + wcol + ni * 16 + m] = (__bf16)acc[mi][ni][r];
      }
    }
  }
}

// ---------------- aggregation ----------------

__device__ __forceinline__ float bflo(unsigned v) {
  return __builtin_bit_cast(float, v << 16);
}
__device__ __forceinline__ float bfhi(unsigned v) {
  return __builtin_bit_cast(float, v & 0xffff0000u);
}

// 128-ch: one wave per node, lane owns channels {2*lane, 2*lane+1}; 4-edge unroll.
template <bool RELU>
__global__ __launch_bounds__(256) void k_agg128(const __bf16* __restrict__ Y,
                                                const __bf16* __restrict__ XR,
                                                const float* __restrict__ bias,
                                                const int* __restrict__ rowptr,
                                                const int* __restrict__ col,
                                                __bf16* __restrict__ out, int nnodes) {
  int wave = threadIdx.x >> 6, lane = threadIdx.x & 63;
  int n = blockIdx.x * 4 + wave;
  if (n >= nnodes) return;
  int beg = rowptr[n], end = rowptr[n + 1];
  float inv = 1.f / (float)max(end - beg, 1);
  int co = lane * 2;

  float a0 = 0.f, a1 = 0.f;
  int j = beg;
  for (; j + 3 < end; j += 4) {
    long s0 = col[j], s1 = col[j + 1], s2 = col[j + 2], s3 = col[j + 3];
    unsigned v0 = *(const unsigned*)(Y + s0 * 128 + co);
    unsigned v1 = *(const unsigned*)(Y + s1 * 128 + co);
    unsigned v2 = *(const unsigned*)(Y + s2 * 128 + co);
    unsigned v3 = *(const unsigned*)(Y + s3 * 128 + co);
    a0 += bflo(v0) + bflo(v1) + bflo(v2) + bflo(v3);
    a1 += bfhi(v0) + bfhi(v1) + bfhi(v2) + bfhi(v3);
  }
  for (; j < end; ++j) {
    long s = col[j];
    unsigned v = *(const unsigned*)(Y + s * 128 + co);
    a0 += bflo(v);
    a1 += bfhi(v);
  }
  unsigned xv = *(const unsigned*)(XR + (long)n * 128 + co);
  float r0 = a0 * inv + bflo(xv) + bias[co];
  float r1 = a1 * inv + bfhi(xv) + bias[co + 1];
  if (RELU) { r0 = fmaxf(r0, 0.f); r1 = fmaxf(r1, 0.f); }
  bf16x2 o;
  o[0] = (__bf16)r0; o[1] = (__bf16)r1;
  *(bf16x2*)(out + (long)n * 128 + co) = o;
}

// 64-ch final: one wave per node; half-wave edge split (lanes<32: even edges,
// lanes>=32: odd edges), lane owns channels {2l, 2l+1}; combine via shfl.
__global__ __launch_bounds__(256) void k_agg64(const __bf16* __restrict__ Y,
                                               const __bf16* __restrict__ XR,
                                               const float* __restrict__ bias,
                                               const int* __restrict__ rowptr,
                                               const int* __restrict__ col,
                                               float* __restrict__ out, int nnodes) {
  int wave = threadIdx.x >> 6, lane = threadIdx.x & 63;
  int n = blockIdx.x * 4 + wave;
  if (n >= nnodes) return;
  int beg = rowptr[n], end = rowptr[n + 1];
  int half = lane >> 5;
  int l = lane & 31;
  int co = l * 2;

  float a0 = 0.f, a1 = 0.f;
  int j = beg;
  for (; j + 7 < end; j += 8) {
    long s0 = col[j + half], s1 = col[j + 2 + half];
    long s2 = col[j + 4 + half], s3 = col[j + 6 + half];
    unsigned v0 = *(const unsigned*)(Y + s0 * 64 + co);
    unsigned v1 = *(const unsigned*)(Y + s1 * 64 + co);
    unsigned v2 = *(const unsigned*)(Y + s2 * 64 + co);
    unsigned v3 = *(const unsigned*)(Y + s3 * 64 + co);
    a0 += bflo(v0) + bflo(v1) + bflo(v2) + bflo(v3);
    a1 += bfhi(v0) + bfhi(v1) + bfhi(v2) + bfhi(v3);
  }
  for (; j + 1 < end; j += 2) {
    long s = col[j + half];
    unsigned v = *(const unsigned*)(Y + s * 64 + co);
    a0 += bflo(v);
    a1 += bfhi(v);
  }
  if (j < end && half == 0) {
    long s = col[j];
    unsigned v = *(const unsigned*)(Y + s * 64 + co);
    a0 += bflo(v);
    a1 += bfhi(v);
  }
  a0 += __shfl_down(a0, 32);
  a1 += __shfl_down(a1, 32);
  if (half == 0) {
    float inv = 1.f / (float)max(end - beg, 1);
    unsigned xv = *(const unsigned*)(XR + (long)n * 64 + co);
    float r0 = a0 * inv + bflo(xv) + bias[co];
    float r1 = a1 * inv + bfhi(xv) + bias[co + 1];
    *(float2*)(out + (long)n * 64 + co) = make_float2(r0, r1);
  }
}

// ---------------- launch ----------------

extern "C" void kernel_launch(void* const* d_in, const int* in_sizes, int n_in,
                              void* d_out, int out_size, void* d_ws, size_t ws_size,
                              hipStream_t stream) {
  const float* x   = (const float*)d_in[0];
  const int*   ei  = (const int*)d_in[1];
  const float* W1l = (const float*)d_in[2];
  const float* W1r = (const float*)d_in[3];
  const float* b1  = (const float*)d_in[4];
  const float* W2l = (const float*)d_in[5];
  const float* W2r = (const float*)d_in[6];
  const float* b2  = (const float*)d_in[7];
  float* out = (float*)d_out;

  int N = in_sizes[0] / K;   // 100000
  int E = in_sizes[1] / 2;   // 1600000
  const int* src = ei;
  const int* dst = ei + E;

  char* ws = (char*)d_ws;
  size_t off = 0;
  auto alloc = [&](size_t bytes) {
    void* p = ws + off;
    off = (off + bytes + 255) & ~(size_t)255;
    return p;
  };
  int*    deg     = (int*)alloc((size_t)N * 4);
  int*    rowptr  = (int*)alloc(((size_t)N + 1) * 4);
  int*    cursor  = (int*)alloc((size_t)N * 4);
  int*    partial = (int*)alloc(256 * 4);
  int*    col     = (int*)alloc((size_t)E * 4);
  __bf16* y1      = (__bf16*)alloc((size_t)N * 128 * 2);
  __bf16* xr      = (__bf16*)alloc((size_t)N * 128 * 2);
  __bf16* h       = (__bf16*)alloc((size_t)N * 128 * 2);
  __bf16* y2 = y1;  // layer-1 buffers dead after k_agg128; reuse
  __bf16* hr = xr;

  int nb = (N + 2047) / 2048;

  hipMemsetAsync(deg, 0, (size_t)N * 4, stream);
  k_count<<<(E + 255) / 256, 256, 0, stream>>>(dst, deg, E, N);
  k_scan_partial<<<nb, 256, 0, stream>>>(deg, partial, N);
  k_scan_top<<<1, 256, 0, stream>>>(partial, nb);
  k_scan_apply<<<nb, 256, 0, stream>>>(deg, partial, rowptr, cursor, N);
  k_fill<<<(E + 255) / 256, 256, 0, stream>>>(src, dst, cursor, col, E, N);

  int gx = (N + 63) / 64;
  // layer 1: y1 = x@W1l, xr = x@W1r; h = relu(mean(y1) + xr + b1)
  k_gemm_mfma<128, float><<<dim3(gx, 2), 256, 0, stream>>>(x, W1l, W1r, y1, xr, N);
  k_agg128<true><<<(N + 3) / 4, 256, 0, stream>>>(y1, xr, b1, rowptr, col, h, N);

  // layer 2: y2 = h@W2l, hr = h@W2r; out = mean(y2) + hr + b2
  k_gemm_mfma<64, __bf16><<<dim3(gx, 2), 256, 0, stream>>>(h, W2l, W2r, y2, hr, N);
  k_agg64<<<(N + 3) / 4, 256, 0, stream>>>(y2, hr, b2, rowptr, col, out, N);
}

// Round 5
// 444.331 us; speedup vs baseline: 2.9707x; 1.1610x over previous
//
#include <hip/hip_runtime.h>
#include <type_traits>

// GraphSAGE 2-layer, N=100k, C 128->128->64, E=1.6M, fp32 in/out.
// R5: bucketed CSR build (kills 16x write amplification of the old k_fill).
// bf16 intermediates + bf16-MFMA GEMMs (fp32 accum).

constexpr int K = 128;
constexpr int EB = 4096;  // edges per partition block

typedef __bf16 bf16x2 __attribute__((ext_vector_type(2)));
typedef __bf16 bf16x4 __attribute__((ext_vector_type(4)));
typedef __bf16 bf16x8 __attribute__((ext_vector_type(8)));
typedef float f32x4 __attribute__((ext_vector_type(4)));

// ---------------- bucketed CSR build ----------------
// bucket = 256 consecutive dst nodes; nB = ceil(N/256) = 391.
// record = (src << 8) | (dst & 255)  (src < 2^17 -> 25 bits, fits u32)

__global__ __launch_bounds__(256) void k_bhist(const int* __restrict__ dst,
                                               int* __restrict__ blockHist,
                                               int E, int n, int nB) {
  extern __shared__ int hist[];
  for (int i = threadIdx.x; i < nB; i += 256) hist[i] = 0;
  __syncthreads();
  int base = blockIdx.x * EB, end = min(base + EB, E);
  for (int e = base + threadIdx.x; e < end; e += 256) {
    int d = dst[e];
    if ((unsigned)d < (unsigned)n) atomicAdd(&hist[d >> 8], 1);
  }
  __syncthreads();
  for (int i = threadIdx.x; i < nB; i += 256)
    blockHist[(long)blockIdx.x * nB + i] = hist[i];
}

__global__ __launch_bounds__(512) void k_bscan(const int* __restrict__ blockHist,
                                               int* __restrict__ bucketBase,
                                               int* __restrict__ bucketCursor,
                                               int nblk, int nB) {
  __shared__ int sh[512];
  int t = threadIdx.x;
  int s = 0;
  if (t < nB)
    for (int b = 0; b < nblk; ++b) s += blockHist[(long)b * nB + t];
  sh[t] = s;
  __syncthreads();
  for (int off = 1; off < 512; off <<= 1) {
    int v = (t >= off) ? sh[t - off] : 0;
    __syncthreads();
    sh[t] += v;
    __syncthreads();
  }
  if (t < nB) {
    int base = sh[t] - s;  // exclusive
    bucketBase[t] = base;
    bucketCursor[t] = base;
    if (t == nB - 1) bucketBase[nB] = sh[t];
  }
}

__global__ __launch_bounds__(256) void k_bscatter(const int* __restrict__ src,
                                                  const int* __restrict__ dst,
                                                  const int* __restrict__ blockHist,
                                                  int* __restrict__ bucketCursor,
                                                  unsigned* __restrict__ recs,
                                                  int E, int n, int nB) {
  extern __shared__ int cur[];
  for (int i = threadIdx.x; i < nB; i += 256) {
    int c = blockHist[(long)blockIdx.x * nB + i];
    cur[i] = c ? atomicAdd(&bucketCursor[i], c) : 0;
  }
  __syncthreads();
  int base = blockIdx.x * EB, end = min(base + EB, E);
  for (int e = base + threadIdx.x; e < end; e += 256) {
    int d = dst[e];
    if ((unsigned)d < (unsigned)n) {
      int s = min(max(src[e], 0), n - 1);
      int pos = atomicAdd(&cur[d >> 8], 1);
      recs[pos] = ((unsigned)s << 8) | (unsigned)(d & 255);
    }
  }
}

__global__ __launch_bounds__(256) void k_bfill(const unsigned* __restrict__ recs,
                                               const int* __restrict__ bucketBase,
                                               int* __restrict__ rowptr,
                                               int* __restrict__ col, int n, int nB) {
  __shared__ int degl[256];
  __shared__ int incl[256];
  int b = blockIdx.x, t = threadIdx.x;
  int rbeg = bucketBase[b], rend = bucketBase[b + 1];
  degl[t] = 0;
  __syncthreads();
  for (int i = rbeg + t; i < rend; i += 256)
    atomicAdd(&degl[recs[i] & 255], 1);
  __syncthreads();
  incl[t] = degl[t];
  __syncthreads();
  for (int off = 1; off < 256; off <<= 1) {
    int v = (t >= off) ? incl[t - off] : 0;
    __syncthreads();
    incl[t] += v;
    __syncthreads();
  }
  int excl = incl[t] - degl[t];
  int node = b * 256 + t;
  if (node <= n) rowptr[node] = rbeg + excl;
  __syncthreads();
  degl[t] = rbeg + excl;  // reuse as cursor
  __syncthreads();
  for (int i = rbeg + t; i < rend; i += 256) {
    unsigned r = recs[i];
    int pos = atomicAdd(&degl[r & 255], 1);
    col[pos] = (int)(r >> 8);
  }
}

// ---------------- bf16 MFMA GEMM ----------------
// out[64 x COLS] = X[64 x 128] @ W[128 x COLS]; blockIdx.y picks (Wa,outA)/(Wb,outB).

template <int COLS, typename TIN>
__global__ __launch_bounds__(256) void k_gemm_mfma(const TIN* __restrict__ X,
                                                   const float* __restrict__ Wa,
                                                   const float* __restrict__ Wb,
                                                   __bf16* __restrict__ outA,
                                                   __bf16* __restrict__ outB, int nrows) {
  constexpr int LD = 136;
  constexpr int MT_N = COLS / 32;
  __shared__ __bf16 sh[(64 + COLS) * LD];
  __bf16* As = sh;
  __bf16* Bt = sh + 64 * LD;

  const float* W = (blockIdx.y == 0) ? Wa : Wb;
  __bf16* outp = (blockIdx.y == 0) ? outA : outB;

  int tid = threadIdx.x;
  long row0 = (long)blockIdx.x * 64;

  if constexpr (std::is_same_v<TIN, float>) {
#pragma unroll
    for (int it = 0; it < 8; ++it) {
      int i = tid + it * 256;
      int r = i >> 5, c4 = (i & 31) << 2;
      long row = row0 + r;
      float4 v = make_float4(0.f, 0.f, 0.f, 0.f);
      if (row < nrows) v = *(const float4*)(X + row * K + c4);
      bf16x4 bb;
      bb[0] = (__bf16)v.x; bb[1] = (__bf16)v.y; bb[2] = (__bf16)v.z; bb[3] = (__bf16)v.w;
      *(bf16x4*)&As[r * LD + c4] = bb;
    }
  } else {
#pragma unroll
    for (int it = 0; it < 4; ++it) {
      int i = tid + it * 256;
      int r = i >> 4, c8 = (i & 15) << 3;
      long row = row0 + r;
      bf16x8 v = {};
      if (row < nrows) v = *(const bf16x8*)(X + row * K + c8);
      *(bf16x8*)&As[r * LD + c8] = v;
    }
  }
  constexpr int C4 = COLS / 4;
#pragma unroll
  for (int it = 0; it < (32 * COLS) / 256; ++it) {
    int i = tid + it * 256;
    int k = i / C4, c = (i % C4) << 2;
    float4 v = *(const float4*)(W + (long)k * COLS + c);
    Bt[(c + 0) * LD + k] = (__bf16)v.x;
    Bt[(c + 1) * LD + k] = (__bf16)v.y;
    Bt[(c + 2) * LD + k] = (__bf16)v.z;
    Bt[(c + 3) * LD + k] = (__bf16)v.w;
  }
  __syncthreads();

  int w = tid >> 6, lane = tid & 63;
  int m = lane & 15, quad = lane >> 4;
  int wrow = (w >> 1) * 32;
  int wcol = (w & 1) * (COLS / 2);

  f32x4 acc[2][MT_N];
#pragma unroll
  for (int mi = 0; mi < 2; ++mi)
#pragma unroll
    for (int ni = 0; ni < MT_N; ++ni) acc[mi][ni] = (f32x4){0.f, 0.f, 0.f, 0.f};

#pragma unroll
  for (int kc = 0; kc < 4; ++kc) {
    int ko = kc * 32 + quad * 8;
    bf16x8 af[2];
#pragma unroll
    for (int mi = 0; mi < 2; ++mi)
      af[mi] = *(const bf16x8*)&As[(wrow + mi * 16 + m) * LD + ko];
    bf16x8 bfr[MT_N];
#pragma unroll
    for (int ni = 0; ni < MT_N; ++ni)
      bfr[ni] = *(const bf16x8*)&Bt[(wcol + ni * 16 + m) * LD + ko];
#pragma unroll
    for (int mi = 0; mi < 2; ++mi)
#pragma unroll
      for (int ni = 0; ni < MT_N; ++ni)
        acc[mi][ni] = __builtin_amdgcn_mfma_f32_16x16x32_bf16(af[mi], bfr[ni], acc[mi][ni], 0, 0, 0);
  }

#pragma unroll
  for (int mi = 0; mi < 2; ++mi) {
#pragma unroll
    for (int r = 0; r < 4; ++r) {
      long grow = row0 + wrow + mi * 16 + quad * 4 + r;
      if (grow < nrows) {
#pragma unroll
        for (int ni = 0; ni < MT_N; ++ni)
          outp[grow * COLS + wcol + ni * 16 + m] = (__bf16)acc[mi][ni][r];
      }
    }
  }
}

// ---------------- aggregation ----------------

__device__ __forceinline__ float bflo(unsigned v) {
  return __builtin_bit_cast(float, v << 16);
}
__device__ __forceinline__ float bfhi(unsigned v) {
  return __builtin_bit_cast(float, v & 0xffff0000u);
}

template <bool RELU>
__global__ __launch_bounds__(256) void k_agg128(const __bf16* __restrict__ Y,
                                                const __bf16* __restrict__ XR,
                                                const float* __restrict__ bias,
                                                const int* __restrict__ rowptr,
                                                const int* __restrict__ col,
                                                __bf16* __restrict__ out, int nnodes) {
  int wave = threadIdx.x >> 6, lane = threadIdx.x & 63;
  int n = blockIdx.x * 4 + wave;
  if (n >= nnodes) return;
  int beg = rowptr[n], end = rowptr[n + 1];
  float inv = 1.f / (float)max(end - beg, 1);
  int co = lane * 2;

  float a0 = 0.f, a1 = 0.f;
  int j = beg;
  for (; j + 3 < end; j += 4) {
    long s0 = col[j], s1 = col[j + 1], s2 = col[j + 2], s3 = col[j + 3];
    unsigned v0 = *(const unsigned*)(Y + s0 * 128 + co);
    unsigned v1 = *(const unsigned*)(Y + s1 * 128 + co);
    unsigned v2 = *(const unsigned*)(Y + s2 * 128 + co);
    unsigned v3 = *(const unsigned*)(Y + s3 * 128 + co);
    a0 += bflo(v0) + bflo(v1) + bflo(v2) + bflo(v3);
    a1 += bfhi(v0) + bfhi(v1) + bfhi(v2) + bfhi(v3);
  }
  for (; j < end; ++j) {
    long s = col[j];
    unsigned v = *(const unsigned*)(Y + s * 128 + co);
    a0 += bflo(v);
    a1 += bfhi(v);
  }
  unsigned xv = *(const unsigned*)(XR + (long)n * 128 + co);
  float r0 = a0 * inv + bflo(xv) + bias[co];
  float r1 = a1 * inv + bfhi(xv) + bias[co + 1];
  if (RELU) { r0 = fmaxf(r0, 0.f); r1 = fmaxf(r1, 0.f); }
  bf16x2 o;
  o[0] = (__bf16)r0; o[1] = (__bf16)r1;
  *(bf16x2*)(out + (long)n * 128 + co) = o;
}

__global__ __launch_bounds__(256) void k_agg64(const __bf16* __restrict__ Y,
                                               const __bf16* __restrict__ XR,
                                               const float* __restrict__ bias,
                                               const int* __restrict__ rowptr,
                                               const int* __restrict__ col,
                                               float* __restrict__ out, int nnodes) {
  int wave = threadIdx.x >> 6, lane = threadIdx.x & 63;
  int n = blockIdx.x * 4 + wave;
  if (n >= nnodes) return;
  int beg = rowptr[n], end = rowptr[n + 1];
  int half = lane >> 5;
  int l = lane & 31;
  int co = l * 2;

  float a0 = 0.f, a1 = 0.f;
  int j = beg;
  for (; j + 7 < end; j += 8) {
    long s0 = col[j + half], s1 = col[j + 2 + half];
    long s2 = col[j + 4 + half], s3 = col[j + 6 + half];
    unsigned v0 = *(const unsigned*)(Y + s0 * 64 + co);
    unsigned v1 = *(const unsigned*)(Y + s1 * 64 + co);
    unsigned v2 = *(const unsigned*)(Y + s2 * 64 + co);
    unsigned v3 = *(const unsigned*)(Y + s3 * 64 + co);
    a0 += bflo(v0) + bflo(v1) + bflo(v2) + bflo(v3);
    a1 += bfhi(v0) + bfhi(v1) + bfhi(v2) + bfhi(v3);
  }
  for (; j + 1 < end; j += 2) {
    long s = col[j + half];
    unsigned v = *(const unsigned*)(Y + s * 64 + co);
    a0 += bflo(v);
    a1 += bfhi(v);
  }
  if (j < end && half == 0) {
    long s = col[j];
    unsigned v = *(const unsigned*)(Y + s * 64 + co);
    a0 += bflo(v);
    a1 += bfhi(v);
  }
  a0 += __shfl_down(a0, 32);
  a1 += __shfl_down(a1, 32);
  if (half == 0) {
    float inv = 1.f / (float)max(end - beg, 1);
    unsigned xv = *(const unsigned*)(XR + (long)n * 64 + co);
    float r0 = a0 * inv + bflo(xv) + bias[co];
    float r1 = a1 * inv + bfhi(xv) + bias[co + 1];
    *(float2*)(out + (long)n * 64 + co) = make_float2(r0, r1);
  }
}

// ---------------- launch ----------------

extern "C" void kernel_launch(void* const* d_in, const int* in_sizes, int n_in,
                              void* d_out, int out_size, void* d_ws, size_t ws_size,
                              hipStream_t stream) {
  const float* x   = (const float*)d_in[0];
  const int*   ei  = (const int*)d_in[1];
  const float* W1l = (const float*)d_in[2];
  const float* W1r = (const float*)d_in[3];
  const float* b1  = (const float*)d_in[4];
  const float* W2l = (const float*)d_in[5];
  const float* W2r = (const float*)d_in[6];
  const float* b2  = (const float*)d_in[7];
  float* out = (float*)d_out;

  int N = in_sizes[0] / K;   // 100000
  int E = in_sizes[1] / 2;   // 1600000
  const int* src = ei;
  const int* dst = ei + E;

  int nB = (N + 255) >> 8;          // 391 buckets
  int nblk = (E + EB - 1) / EB;     // 391 partition blocks

  char* ws = (char*)d_ws;
  size_t off = 0;
  auto alloc = [&](size_t bytes) {
    void* p = ws + off;
    off = (off + bytes + 255) & ~(size_t)255;
    return p;
  };
  int*      rowptr    = (int*)alloc(((size_t)N + 2) * 4);
  int*      col       = (int*)alloc((size_t)E * 4);
  int*      blockHist = (int*)alloc((size_t)nblk * nB * 4);
  int*      bucketBase   = (int*)alloc(((size_t)nB + 1) * 4);
  int*      bucketCursor = (int*)alloc((size_t)nB * 4);
  unsigned* recs      = (unsigned*)alloc((size_t)E * 4);
  __bf16*   y1        = (__bf16*)alloc((size_t)N * 128 * 2);
  __bf16*   xr        = (__bf16*)alloc((size_t)N * 128 * 2);
  __bf16*   h         = (__bf16*)alloc((size_t)N * 128 * 2);
  __bf16* y2 = y1;  // layer-1 buffers dead after k_agg128; reuse
  __bf16* hr = xr;

  // CSR build (bucketed)
  k_bhist<<<nblk, 256, nB * 4, stream>>>(dst, blockHist, E, N, nB);
  k_bscan<<<1, 512, 0, stream>>>(blockHist, bucketBase, bucketCursor, nblk, nB);
  k_bscatter<<<nblk, 256, nB * 4, stream>>>(src, dst, blockHist, bucketCursor, recs, E, N, nB);
  k_bfill<<<nB, 256, 0, stream>>>(recs, bucketBase, rowptr, col, N, nB);

  int gx = (N + 63) / 64;
  // layer 1: y1 = x@W1l, xr = x@W1r; h = relu(mean(y1) + xr + b1)
  k_gemm_mfma<128, float><<<dim3(gx, 2), 256, 0, stream>>>(x, W1l, W1r, y1, xr, N);
  k_agg128<true><<<(N + 3) / 4, 256, 0, stream>>>(y1, xr, b1, rowptr, col, h, N);

  // layer 2: y2 = h@W2l, hr = h@W2r; out = mean(y2) + hr + b2
  k_gemm_mfma<64, __bf16><<<dim3(gx, 2), 256, 0, stream>>>(h, W2l, W2r, y2, hr, N);
  k_agg64<<<(N + 3) / 4, 256, 0, stream>>>(y2, hr, b2, rowptr, col, out, N);
}

// Round 6
// 362.718 us; speedup vs baseline: 3.6391x; 1.2250x over previous
//
#include <hip/hip_runtime.h>
#include <type_traits>

// GraphSAGE 2-layer, N=100k, C 128->128->64, E=1.6M, fp32 in/out.
// R6: bucket totals via atomics in k_bhist (kills 100us single-block column-sum).
// Bucketed CSR build + bf16 intermediates + bf16-MFMA GEMMs.

constexpr int K = 128;
constexpr int EB = 4096;  // edges per partition block

typedef __bf16 bf16x2 __attribute__((ext_vector_type(2)));
typedef __bf16 bf16x4 __attribute__((ext_vector_type(4)));
typedef __bf16 bf16x8 __attribute__((ext_vector_type(8)));
typedef float f32x4 __attribute__((ext_vector_type(4)));

// ---------------- bucketed CSR build ----------------
// bucket = 256 consecutive dst nodes; nB = ceil(N/256) = 391.
// record = (src << 8) | (dst & 255)  (src < 2^17 -> 25 bits, fits u32)

__global__ __launch_bounds__(256) void k_bhist(const int* __restrict__ dst,
                                               int* __restrict__ blockHist,
                                               int* __restrict__ bucketTotal,
                                               int E, int n, int nB) {
  extern __shared__ int hist[];
  for (int i = threadIdx.x; i < nB; i += 256) hist[i] = 0;
  __syncthreads();
  int base = blockIdx.x * EB, end = min(base + EB, E);
  for (int e = base + threadIdx.x; e < end; e += 256) {
    int d = dst[e];
    if ((unsigned)d < (unsigned)n) atomicAdd(&hist[d >> 8], 1);
  }
  __syncthreads();
  for (int i = threadIdx.x; i < nB; i += 256) {
    int v = hist[i];
    blockHist[(long)blockIdx.x * nB + i] = v;
    if (v) atomicAdd(&bucketTotal[i], v);
  }
}

// tiny single-block scan over nB (<=512) bucket totals
__global__ __launch_bounds__(512) void k_btop(const int* __restrict__ bucketTotal,
                                              int* __restrict__ bucketBase,
                                              int* __restrict__ bucketCursor, int nB) {
  __shared__ int sh[512];
  int t = threadIdx.x;
  int s = (t < nB) ? bucketTotal[t] : 0;
  sh[t] = s;
  __syncthreads();
  for (int off = 1; off < 512; off <<= 1) {
    int v = (t >= off) ? sh[t - off] : 0;
    __syncthreads();
    sh[t] += v;
    __syncthreads();
  }
  if (t < nB) {
    int base = sh[t] - s;  // exclusive
    bucketBase[t] = base;
    bucketCursor[t] = base;
    if (t == nB - 1) bucketBase[nB] = sh[t];
  }
}

__global__ __launch_bounds__(256) void k_bscatter(const int* __restrict__ src,
                                                  const int* __restrict__ dst,
                                                  const int* __restrict__ blockHist,
                                                  int* __restrict__ bucketCursor,
                                                  unsigned* __restrict__ recs,
                                                  int E, int n, int nB) {
  extern __shared__ int cur[];
  for (int i = threadIdx.x; i < nB; i += 256) {
    int c = blockHist[(long)blockIdx.x * nB + i];
    cur[i] = c ? atomicAdd(&bucketCursor[i], c) : 0;
  }
  __syncthreads();
  int base = blockIdx.x * EB, end = min(base + EB, E);
  for (int e = base + threadIdx.x; e < end; e += 256) {
    int d = dst[e];
    if ((unsigned)d < (unsigned)n) {
      int s = min(max(src[e], 0), n - 1);
      int pos = atomicAdd(&cur[d >> 8], 1);
      recs[pos] = ((unsigned)s << 8) | (unsigned)(d & 255);
    }
  }
}

__global__ __launch_bounds__(256) void k_bfill(const unsigned* __restrict__ recs,
                                               const int* __restrict__ bucketBase,
                                               int* __restrict__ rowptr,
                                               int* __restrict__ col, int n, int nB) {
  __shared__ int degl[256];
  __shared__ int incl[256];
  int b = blockIdx.x, t = threadIdx.x;
  int rbeg = bucketBase[b], rend = bucketBase[b + 1];
  degl[t] = 0;
  __syncthreads();
  for (int i = rbeg + t; i < rend; i += 256)
    atomicAdd(&degl[recs[i] & 255], 1);
  __syncthreads();
  incl[t] = degl[t];
  __syncthreads();
  for (int off = 1; off < 256; off <<= 1) {
    int v = (t >= off) ? incl[t - off] : 0;
    __syncthreads();
    incl[t] += v;
    __syncthreads();
  }
  int excl = incl[t] - degl[t];
  int node = b * 256 + t;
  if (node <= n) rowptr[node] = rbeg + excl;
  __syncthreads();
  degl[t] = rbeg + excl;  // reuse as cursor
  __syncthreads();
  for (int i = rbeg + t; i < rend; i += 256) {
    unsigned r = recs[i];
    int pos = atomicAdd(&degl[r & 255], 1);
    col[pos] = (int)(r >> 8);
  }
}

// ---------------- bf16 MFMA GEMM ----------------
// out[64 x COLS] = X[64 x 128] @ W[128 x COLS]; blockIdx.y picks (Wa,outA)/(Wb,outB).

template <int COLS, typename TIN>
__global__ __launch_bounds__(256) void k_gemm_mfma(const TIN* __restrict__ X,
                                                   const float* __restrict__ Wa,
                                                   const float* __restrict__ Wb,
                                                   __bf16* __restrict__ outA,
                                                   __bf16* __restrict__ outB, int nrows) {
  constexpr int LD = 136;
  constexpr int MT_N = COLS / 32;
  __shared__ __bf16 sh[(64 + COLS) * LD];
  __bf16* As = sh;
  __bf16* Bt = sh + 64 * LD;

  const float* W = (blockIdx.y == 0) ? Wa : Wb;
  __bf16* outp = (blockIdx.y == 0) ? outA : outB;

  int tid = threadIdx.x;
  long row0 = (long)blockIdx.x * 64;

  if constexpr (std::is_same_v<TIN, float>) {
#pragma unroll
    for (int it = 0; it < 8; ++it) {
      int i = tid + it * 256;
      int r = i >> 5, c4 = (i & 31) << 2;
      long row = row0 + r;
      float4 v = make_float4(0.f, 0.f, 0.f, 0.f);
      if (row < nrows) v = *(const float4*)(X + row * K + c4);
      bf16x4 bb;
      bb[0] = (__bf16)v.x; bb[1] = (__bf16)v.y; bb[2] = (__bf16)v.z; bb[3] = (__bf16)v.w;
      *(bf16x4*)&As[r * LD + c4] = bb;
    }
  } else {
#pragma unroll
    for (int it = 0; it < 4; ++it) {
      int i = tid + it * 256;
      int r = i >> 4, c8 = (i & 15) << 3;
      long row = row0 + r;
      bf16x8 v = {};
      if (row < nrows) v = *(const bf16x8*)(X + row * K + c8);
      *(bf16x8*)&As[r * LD + c8] = v;
    }
  }
  constexpr int C4 = COLS / 4;
#pragma unroll
  for (int it = 0; it < (32 * COLS) / 256; ++it) {
    int i = tid + it * 256;
    int k = i / C4, c = (i % C4) << 2;
    float4 v = *(const float4*)(W + (long)k * COLS + c);
    Bt[(c + 0) * LD + k] = (__bf16)v.x;
    Bt[(c + 1) * LD + k] = (__bf16)v.y;
    Bt[(c + 2) * LD + k] = (__bf16)v.z;
    Bt[(c + 3) * LD + k] = (__bf16)v.w;
  }
  __syncthreads();

  int w = tid >> 6, lane = tid & 63;
  int m = lane & 15, quad = lane >> 4;
  int wrow = (w >> 1) * 32;
  int wcol = (w & 1) * (COLS / 2);

  f32x4 acc[2][MT_N];
#pragma unroll
  for (int mi = 0; mi < 2; ++mi)
#pragma unroll
    for (int ni = 0; ni < MT_N; ++ni) acc[mi][ni] = (f32x4){0.f, 0.f, 0.f, 0.f};

#pragma unroll
  for (int kc = 0; kc < 4; ++kc) {
    int ko = kc * 32 + quad * 8;
    bf16x8 af[2];
#pragma unroll
    for (int mi = 0; mi < 2; ++mi)
      af[mi] = *(const bf16x8*)&As[(wrow + mi * 16 + m) * LD + ko];
    bf16x8 bfr[MT_N];
#pragma unroll
    for (int ni = 0; ni < MT_N; ++ni)
      bfr[ni] = *(const bf16x8*)&Bt[(wcol + ni * 16 + m) * LD + ko];
#pragma unroll
    for (int mi = 0; mi < 2; ++mi)
#pragma unroll
      for (int ni = 0; ni < MT_N; ++ni)
        acc[mi][ni] = __builtin_amdgcn_mfma_f32_16x16x32_bf16(af[mi], bfr[ni], acc[mi][ni], 0, 0, 0);
  }

#pragma unroll
  for (int mi = 0; mi < 2; ++mi) {
#pragma unroll
    for (int r = 0; r < 4; ++r) {
      long grow = row0 + wrow + mi * 16 + quad * 4 + r;
      if (grow < nrows) {
#pragma unroll
        for (int ni = 0; ni < MT_N; ++ni)
          outp[grow * COLS + wcol + ni * 16 + m] = (__bf16)acc[mi][ni][r];
      }
    }
  }
}

// ---------------- aggregation ----------------

__device__ __forceinline__ float bflo(unsigned v) {
  return __builtin_bit_cast(float, v << 16);
}
__device__ __forceinline__ float bfhi(unsigned v) {
  return __builtin_bit_cast(float, v & 0xffff0000u);
}

template <bool RELU>
__global__ __launch_bounds__(256) void k_agg128(const __bf16* __restrict__ Y,
                                                const __bf16* __restrict__ XR,
                                                const float* __restrict__ bias,
                                                const int* __restrict__ rowptr,
                                                const int* __restrict__ col,
                                                __bf16* __restrict__ out, int nnodes) {
  int wave = threadIdx.x >> 6, lane = threadIdx.x & 63;
  int n = blockIdx.x * 4 + wave;
  if (n >= nnodes) return;
  int beg = rowptr[n], end = rowptr[n + 1];
  float inv = 1.f / (float)max(end - beg, 1);
  int co = lane * 2;

  float a0 = 0.f, a1 = 0.f;
  int j = beg;
  for (; j + 3 < end; j += 4) {
    long s0 = col[j], s1 = col[j + 1], s2 = col[j + 2], s3 = col[j + 3];
    unsigned v0 = *(const unsigned*)(Y + s0 * 128 + co);
    unsigned v1 = *(const unsigned*)(Y + s1 * 128 + co);
    unsigned v2 = *(const unsigned*)(Y + s2 * 128 + co);
    unsigned v3 = *(const unsigned*)(Y + s3 * 128 + co);
    a0 += bflo(v0) + bflo(v1) + bflo(v2) + bflo(v3);
    a1 += bfhi(v0) + bfhi(v1) + bfhi(v2) + bfhi(v3);
  }
  for (; j < end; ++j) {
    long s = col[j];
    unsigned v = *(const unsigned*)(Y + s * 128 + co);
    a0 += bflo(v);
    a1 += bfhi(v);
  }
  unsigned xv = *(const unsigned*)(XR + (long)n * 128 + co);
  float r0 = a0 * inv + bflo(xv) + bias[co];
  float r1 = a1 * inv + bfhi(xv) + bias[co + 1];
  if (RELU) { r0 = fmaxf(r0, 0.f); r1 = fmaxf(r1, 0.f); }
  bf16x2 o;
  o[0] = (__bf16)r0; o[1] = (__bf16)r1;
  *(bf16x2*)(out + (long)n * 128 + co) = o;
}

__global__ __launch_bounds__(256) void k_agg64(const __bf16* __restrict__ Y,
                                               const __bf16* __restrict__ XR,
                                               const float* __restrict__ bias,
                                               const int* __restrict__ rowptr,
                                               const int* __restrict__ col,
                                               float* __restrict__ out, int nnodes) {
  int wave = threadIdx.x >> 6, lane = threadIdx.x & 63;
  int n = blockIdx.x * 4 + wave;
  if (n >= nnodes) return;
  int beg = rowptr[n], end = rowptr[n + 1];
  int half = lane >> 5;
  int l = lane & 31;
  int co = l * 2;

  float a0 = 0.f, a1 = 0.f;
  int j = beg;
  for (; j + 7 < end; j += 8) {
    long s0 = col[j + half], s1 = col[j + 2 + half];
    long s2 = col[j + 4 + half], s3 = col[j + 6 + half];
    unsigned v0 = *(const unsigned*)(Y + s0 * 64 + co);
    unsigned v1 = *(const unsigned*)(Y + s1 * 64 + co);
    unsigned v2 = *(const unsigned*)(Y + s2 * 64 + co);
    unsigned v3 = *(const unsigned*)(Y + s3 * 64 + co);
    a0 += bflo(v0) + bflo(v1) + bflo(v2) + bflo(v3);
    a1 += bfhi(v0) + bfhi(v1) + bfhi(v2) + bfhi(v3);
  }
  for (; j + 1 < end; j += 2) {
    long s = col[j + half];
    unsigned v = *(const unsigned*)(Y + s * 64 + co);
    a0 += bflo(v);
    a1 += bfhi(v);
  }
  if (j < end && half == 0) {
    long s = col[j];
    unsigned v = *(const unsigned*)(Y + s * 64 + co);
    a0 += bflo(v);
    a1 += bfhi(v);
  }
  a0 += __shfl_down(a0, 32);
  a1 += __shfl_down(a1, 32);
  if (half == 0) {
    float inv = 1.f / (float)max(end - beg, 1);
    unsigned xv = *(const unsigned*)(XR + (long)n * 64 + co);
    float r0 = a0 * inv + bflo(xv) + bias[co];
    float r1 = a1 * inv + bfhi(xv) + bias[co + 1];
    *(float2*)(out + (long)n * 64 + co) = make_float2(r0, r1);
  }
}

// ---------------- launch ----------------

extern "C" void kernel_launch(void* const* d_in, const int* in_sizes, int n_in,
                              void* d_out, int out_size, void* d_ws, size_t ws_size,
                              hipStream_t stream) {
  const float* x   = (const float*)d_in[0];
  const int*   ei  = (const int*)d_in[1];
  const float* W1l = (const float*)d_in[2];
  const float* W1r = (const float*)d_in[3];
  const float* b1  = (const float*)d_in[4];
  const float* W2l = (const float*)d_in[5];
  const float* W2r = (const float*)d_in[6];
  const float* b2  = (const float*)d_in[7];
  float* out = (float*)d_out;

  int N = in_sizes[0] / K;   // 100000
  int E = in_sizes[1] / 2;   // 1600000
  const int* src = ei;
  const int* dst = ei + E;

  int nB = (N + 255) >> 8;          // 391 buckets
  int nblk = (E + EB - 1) / EB;     // 391 partition blocks

  char* ws = (char*)d_ws;
  size_t off = 0;
  auto alloc = [&](size_t bytes) {
    void* p = ws + off;
    off = (off + bytes + 255) & ~(size_t)255;
    return p;
  };
  int*      rowptr       = (int*)alloc(((size_t)N + 2) * 4);
  int*      col          = (int*)alloc((size_t)E * 4);
  int*      blockHist    = (int*)alloc((size_t)nblk * nB * 4);
  int*      bucketTotal  = (int*)alloc(((size_t)nB) * 4);
  int*      bucketBase   = (int*)alloc(((size_t)nB + 1) * 4);
  int*      bucketCursor = (int*)alloc((size_t)nB * 4);
  unsigned* recs         = (unsigned*)alloc((size_t)E * 4);
  __bf16*   y1           = (__bf16*)alloc((size_t)N * 128 * 2);
  __bf16*   xr           = (__bf16*)alloc((size_t)N * 128 * 2);
  __bf16*   h            = (__bf16*)alloc((size_t)N * 128 * 2);
  __bf16* y2 = y1;  // layer-1 buffers dead after k_agg128; reuse
  __bf16* hr = xr;

  // CSR build (bucketed)
  hipMemsetAsync(bucketTotal, 0, (size_t)nB * 4, stream);
  k_bhist<<<nblk, 256, nB * 4, stream>>>(dst, blockHist, bucketTotal, E, N, nB);
  k_btop<<<1, 512, 0, stream>>>(bucketTotal, bucketBase, bucketCursor, nB);
  k_bscatter<<<nblk, 256, nB * 4, stream>>>(src, dst, blockHist, bucketCursor, recs, E, N, nB);
  k_bfill<<<nB, 256, 0, stream>>>(recs, bucketBase, rowptr, col, N, nB);

  int gx = (N + 63) / 64;
  // layer 1: y1 = x@W1l, xr = x@W1r; h = relu(mean(y1) + xr + b1)
  k_gemm_mfma<128, float><<<dim3(gx, 2), 256, 0, stream>>>(x, W1l, W1r, y1, xr, N);
  k_agg128<true><<<(N + 3) / 4, 256, 0, stream>>>(y1, xr, b1, rowptr, col, h, N);

  // layer 2: y2 = h@W2l, hr = h@W2r; out = mean(y2) + hr + b2
  k_gemm_mfma<64, __bf16><<<dim3(gx, 2), 256, 0, stream>>>(h, W2l, W2r, y2, hr, N);
  k_agg64<<<(N + 3) / 4, 256, 0, stream>>>(y2, hr, b2, rowptr, col, out, N);
}

// Round 7
// 358.691 us; speedup vs baseline: 3.6799x; 1.0112x over previous
//
#include <hip/hip_runtime.h>
#include <type_traits>

// GraphSAGE 2-layer, N=100k, C 128->128->64, E=1.6M, fp32 in/out.
// R7: fp8(e4m3) gather buffers y1/y2 (halves random-gather bytes; self-path
// xr/hr and GEMM input h stay bf16). Bucketed CSR build, bf16-MFMA GEMMs.

constexpr int K = 128;
constexpr int EB = 4096;  // edges per partition block

typedef __bf16 bf16x2 __attribute__((ext_vector_type(2)));
typedef __bf16 bf16x4 __attribute__((ext_vector_type(4)));
typedef __bf16 bf16x8 __attribute__((ext_vector_type(8)));
typedef float f32x4 __attribute__((ext_vector_type(4)));
typedef float f32x2 __attribute__((ext_vector_type(2)));

// ---------------- fp8 e4m3 conversion ----------------

__device__ __forceinline__ unsigned char to_fp8(float v) {
#if __has_builtin(__builtin_amdgcn_cvt_pk_fp8_f32)
  int p = __builtin_amdgcn_cvt_pk_fp8_f32(v, v, 0, false);
  return (unsigned char)(p & 0xff);
#else
  unsigned u = __builtin_bit_cast(unsigned, v);
  unsigned s = (u >> 24) & 0x80u;
  float a = fabsf(v);
  if (a > 448.f) a = 448.f;
  unsigned bits;
  if (a < 0.015625f) {  // subnormal: step 2^-9
    bits = (unsigned)(a * 512.f + 0.5f);
  } else {
    unsigned b = __builtin_bit_cast(unsigned, a);
    b += ((b >> 20) & 1) + 0x0007FFFF;  // RNE to 3 mantissa bits
    unsigned e = (b >> 23) - 120;
    bits = (e << 3) | ((b >> 20) & 7);
    if (bits > 0x7E) bits = 0x7E;  // clamp to 448
  }
  return (unsigned char)(s | bits);
#endif
}

__device__ __forceinline__ f32x2 from_fp8x2(unsigned short u) {
#if __has_builtin(__builtin_amdgcn_cvt_pk_f32_fp8)
  return __builtin_amdgcn_cvt_pk_f32_fp8((int)u, false);
#else
  f32x2 r;
  unsigned b0 = u & 0xff, b1 = (u >> 8) & 0xff;
  unsigned e0 = (b0 >> 3) & 15, m0 = b0 & 7;
  unsigned e1 = (b1 >> 3) & 15, m1 = b1 & 7;
  float v0 = e0 ? __builtin_bit_cast(float, ((e0 + 120) << 23) | (m0 << 20))
              : (float)m0 * 0.001953125f;
  float v1 = e1 ? __builtin_bit_cast(float, ((e1 + 120) << 23) | (m1 << 20))
              : (float)m1 * 0.001953125f;
  r[0] = (b0 & 0x80) ? -v0 : v0;
  r[1] = (b1 & 0x80) ? -v1 : v1;
  return r;
#endif
}

// ---------------- bucketed CSR build ----------------

__global__ __launch_bounds__(256) void k_bhist(const int* __restrict__ dst,
                                               int* __restrict__ blockHist,
                                               int* __restrict__ bucketTotal,
                                               int E, int n, int nB) {
  extern __shared__ int hist[];
  for (int i = threadIdx.x; i < nB; i += 256) hist[i] = 0;
  __syncthreads();
  int base = blockIdx.x * EB, end = min(base + EB, E);
  for (int e = base + threadIdx.x; e < end; e += 256) {
    int d = dst[e];
    if ((unsigned)d < (unsigned)n) atomicAdd(&hist[d >> 8], 1);
  }
  __syncthreads();
  for (int i = threadIdx.x; i < nB; i += 256) {
    int v = hist[i];
    blockHist[(long)blockIdx.x * nB + i] = v;
    if (v) atomicAdd(&bucketTotal[i], v);
  }
}

__global__ __launch_bounds__(512) void k_btop(const int* __restrict__ bucketTotal,
                                              int* __restrict__ bucketBase,
                                              int* __restrict__ bucketCursor, int nB) {
  __shared__ int sh[512];
  int t = threadIdx.x;
  int s = (t < nB) ? bucketTotal[t] : 0;
  sh[t] = s;
  __syncthreads();
  for (int off = 1; off < 512; off <<= 1) {
    int v = (t >= off) ? sh[t - off] : 0;
    __syncthreads();
    sh[t] += v;
    __syncthreads();
  }
  if (t < nB) {
    int base = sh[t] - s;
    bucketBase[t] = base;
    bucketCursor[t] = base;
    if (t == nB - 1) bucketBase[nB] = sh[t];
  }
}

__global__ __launch_bounds__(256) void k_bscatter(const int* __restrict__ src,
                                                  const int* __restrict__ dst,
                                                  const int* __restrict__ blockHist,
                                                  int* __restrict__ bucketCursor,
                                                  unsigned* __restrict__ recs,
                                                  int E, int n, int nB) {
  extern __shared__ int cur[];
  for (int i = threadIdx.x; i < nB; i += 256) {
    int c = blockHist[(long)blockIdx.x * nB + i];
    cur[i] = c ? atomicAdd(&bucketCursor[i], c) : 0;
  }
  __syncthreads();
  int base = blockIdx.x * EB, end = min(base + EB, E);
  for (int e = base + threadIdx.x; e < end; e += 256) {
    int d = dst[e];
    if ((unsigned)d < (unsigned)n) {
      int s = min(max(src[e], 0), n - 1);
      int pos = atomicAdd(&cur[d >> 8], 1);
      recs[pos] = ((unsigned)s << 8) | (unsigned)(d & 255);
    }
  }
}

__global__ __launch_bounds__(256) void k_bfill(const unsigned* __restrict__ recs,
                                               const int* __restrict__ bucketBase,
                                               int* __restrict__ rowptr,
                                               int* __restrict__ col, int n, int nB) {
  __shared__ int degl[256];
  __shared__ int incl[256];
  int b = blockIdx.x, t = threadIdx.x;
  int rbeg = bucketBase[b], rend = bucketBase[b + 1];
  degl[t] = 0;
  __syncthreads();
  for (int i = rbeg + t; i < rend; i += 256)
    atomicAdd(&degl[recs[i] & 255], 1);
  __syncthreads();
  incl[t] = degl[t];
  __syncthreads();
  for (int off = 1; off < 256; off <<= 1) {
    int v = (t >= off) ? incl[t - off] : 0;
    __syncthreads();
    incl[t] += v;
    __syncthreads();
  }
  int excl = incl[t] - degl[t];
  int node = b * 256 + t;
  if (node <= n) rowptr[node] = rbeg + excl;
  __syncthreads();
  degl[t] = rbeg + excl;  // reuse as cursor
  __syncthreads();
  for (int i = rbeg + t; i < rend; i += 256) {
    unsigned r = recs[i];
    int pos = atomicAdd(&degl[r & 255], 1);
    col[pos] = (int)(r >> 8);
  }
}

// ---------------- bf16 MFMA GEMM ----------------
// blockIdx.y==0: outA (fp8, gather path); ==1: outB (bf16, self path).

template <int COLS, typename TIN>
__global__ __launch_bounds__(256) void k_gemm_mfma(const TIN* __restrict__ X,
                                                   const float* __restrict__ Wa,
                                                   const float* __restrict__ Wb,
                                                   unsigned char* __restrict__ outA,
                                                   __bf16* __restrict__ outB, int nrows) {
  constexpr int LD = 136;
  constexpr int MT_N = COLS / 32;
  __shared__ __bf16 sh[(64 + COLS) * LD];
  __bf16* As = sh;
  __bf16* Bt = sh + 64 * LD;

  bool isA = (blockIdx.y == 0);
  const float* W = isA ? Wa : Wb;

  int tid = threadIdx.x;
  long row0 = (long)blockIdx.x * 64;

  if constexpr (std::is_same_v<TIN, float>) {
#pragma unroll
    for (int it = 0; it < 8; ++it) {
      int i = tid + it * 256;
      int r = i >> 5, c4 = (i & 31) << 2;
      long row = row0 + r;
      float4 v = make_float4(0.f, 0.f, 0.f, 0.f);
      if (row < nrows) v = *(const float4*)(X + row * K + c4);
      bf16x4 bb;
      bb[0] = (__bf16)v.x; bb[1] = (__bf16)v.y; bb[2] = (__bf16)v.z; bb[3] = (__bf16)v.w;
      *(bf16x4*)&As[r * LD + c4] = bb;
    }
  } else {
#pragma unroll
    for (int it = 0; it < 4; ++it) {
      int i = tid + it * 256;
      int r = i >> 4, c8 = (i & 15) << 3;
      long row = row0 + r;
      bf16x8 v = {};
      if (row < nrows) v = *(const bf16x8*)(X + row * K + c8);
      *(bf16x8*)&As[r * LD + c8] = v;
    }
  }
  constexpr int C4 = COLS / 4;
#pragma unroll
  for (int it = 0; it < (32 * COLS) / 256; ++it) {
    int i = tid + it * 256;
    int k = i / C4, c = (i % C4) << 2;
    float4 v = *(const float4*)(W + (long)k * COLS + c);
    Bt[(c + 0) * LD + k] = (__bf16)v.x;
    Bt[(c + 1) * LD + k] = (__bf16)v.y;
    Bt[(c + 2) * LD + k] = (__bf16)v.z;
    Bt[(c + 3) * LD + k] = (__bf16)v.w;
  }
  __syncthreads();

  int w = tid >> 6, lane = tid & 63;
  int m = lane & 15, quad = lane >> 4;
  int wrow = (w >> 1) * 32;
  int wcol = (w & 1) * (COLS / 2);

  f32x4 acc[2][MT_N];
#pragma unroll
  for (int mi = 0; mi < 2; ++mi)
#pragma unroll
    for (int ni = 0; ni < MT_N; ++ni) acc[mi][ni] = (f32x4){0.f, 0.f, 0.f, 0.f};

#pragma unroll
  for (int kc = 0; kc < 4; ++kc) {
    int ko = kc * 32 + quad * 8;
    bf16x8 af[2];
#pragma unroll
    for (int mi = 0; mi < 2; ++mi)
      af[mi] = *(const bf16x8*)&As[(wrow + mi * 16 + m) * LD + ko];
    bf16x8 bfr[MT_N];
#pragma unroll
    for (int ni = 0; ni < MT_N; ++ni)
      bfr[ni] = *(const bf16x8*)&Bt[(wcol + ni * 16 + m) * LD + ko];
#pragma unroll
    for (int mi = 0; mi < 2; ++mi)
#pragma unroll
      for (int ni = 0; ni < MT_N; ++ni)
        acc[mi][ni] = __builtin_amdgcn_mfma_f32_16x16x32_bf16(af[mi], bfr[ni], acc[mi][ni], 0, 0, 0);
  }

#pragma unroll
  for (int mi = 0; mi < 2; ++mi) {
#pragma unroll
    for (int r = 0; r < 4; ++r) {
      long grow = row0 + wrow + mi * 16 + quad * 4 + r;
      if (grow < nrows) {
#pragma unroll
        for (int ni = 0; ni < MT_N; ++ni) {
          long idx = grow * COLS + wcol + ni * 16 + m;
          float v = acc[mi][ni][r];
          if (isA) outA[idx] = to_fp8(v);
          else     outB[idx] = (__bf16)v;
        }
      }
    }
  }
}

// ---------------- aggregation ----------------

template <bool RELU>
__global__ __launch_bounds__(256) void k_agg128(const unsigned char* __restrict__ Y,
                                                const __bf16* __restrict__ XR,
                                                const float* __restrict__ bias,
                                                const int* __restrict__ rowptr,
                                                const int* __restrict__ col,
                                                __bf16* __restrict__ out, int nnodes) {
  int wave = threadIdx.x >> 6, lane = threadIdx.x & 63;
  int n = blockIdx.x * 4 + wave;
  if (n >= nnodes) return;
  int beg = rowptr[n], end = rowptr[n + 1];
  float inv = 1.f / (float)max(end - beg, 1);
  int co = lane * 2;  // channel pair; byte offset co in fp8 row (128 B)

  float a0 = 0.f, a1 = 0.f;
  int j = beg;
  for (; j + 3 < end; j += 4) {
    long s0 = col[j], s1 = col[j + 1], s2 = col[j + 2], s3 = col[j + 3];
    unsigned short v0 = *(const unsigned short*)(Y + s0 * 128 + co);
    unsigned short v1 = *(const unsigned short*)(Y + s1 * 128 + co);
    unsigned short v2 = *(const unsigned short*)(Y + s2 * 128 + co);
    unsigned short v3 = *(const unsigned short*)(Y + s3 * 128 + co);
    f32x2 f0 = from_fp8x2(v0), f1 = from_fp8x2(v1);
    f32x2 f2 = from_fp8x2(v2), f3 = from_fp8x2(v3);
    a0 += f0[0] + f1[0] + f2[0] + f3[0];
    a1 += f0[1] + f1[1] + f2[1] + f3[1];
  }
  for (; j < end; ++j) {
    long s = col[j];
    f32x2 f = from_fp8x2(*(const unsigned short*)(Y + s * 128 + co));
    a0 += f[0];
    a1 += f[1];
  }
  unsigned xv = *(const unsigned*)(XR + (long)n * 128 + co);
  float x0 = __builtin_bit_cast(float, xv << 16);
  float x1 = __builtin_bit_cast(float, xv & 0xffff0000u);
  float r0 = a0 * inv + x0 + bias[co];
  float r1 = a1 * inv + x1 + bias[co + 1];
  if (RELU) { r0 = fmaxf(r0, 0.f); r1 = fmaxf(r1, 0.f); }
  bf16x2 o;
  o[0] = (__bf16)r0; o[1] = (__bf16)r1;
  *(bf16x2*)(out + (long)n * 128 + co) = o;
}

// 64-ch final: half-wave edge split; lane owns 2 channels (2 B fp8 per edge).
__global__ __launch_bounds__(256) void k_agg64(const unsigned char* __restrict__ Y,
                                               const __bf16* __restrict__ XR,
                                               const float* __restrict__ bias,
                                               const int* __restrict__ rowptr,
                                               const int* __restrict__ col,
                                               float* __restrict__ out, int nnodes) {
  int wave = threadIdx.x >> 6, lane = threadIdx.x & 63;
  int n = blockIdx.x * 4 + wave;
  if (n >= nnodes) return;
  int beg = rowptr[n], end = rowptr[n + 1];
  int half = lane >> 5;
  int l = lane & 31;
  int co = l * 2;  // byte offset in fp8 row (64 B)

  float a0 = 0.f, a1 = 0.f;
  int j = beg;
  for (; j + 7 < end; j += 8) {
    long s0 = col[j + half], s1 = col[j + 2 + half];
    long s2 = col[j + 4 + half], s3 = col[j + 6 + half];
    f32x2 f0 = from_fp8x2(*(const unsigned short*)(Y + s0 * 64 + co));
    f32x2 f1 = from_fp8x2(*(const unsigned short*)(Y + s1 * 64 + co));
    f32x2 f2 = from_fp8x2(*(const unsigned short*)(Y + s2 * 64 + co));
    f32x2 f3 = from_fp8x2(*(const unsigned short*)(Y + s3 * 64 + co));
    a0 += f0[0] + f1[0] + f2[0] + f3[0];
    a1 += f0[1] + f1[1] + f2[1] + f3[1];
  }
  for (; j + 1 < end; j += 2) {
    long s = col[j + half];
    f32x2 f = from_fp8x2(*(const unsigned short*)(Y + s * 64 + co));
    a0 += f[0];
    a1 += f[1];
  }
  if (j < end && half == 0) {
    long s = col[j];
    f32x2 f = from_fp8x2(*(const unsigned short*)(Y + s * 64 + co));
    a0 += f[0];
    a1 += f[1];
  }
  a0 += __shfl_down(a0, 32);
  a1 += __shfl_down(a1, 32);
  if (half == 0) {
    float inv = 1.f / (float)max(end - beg, 1);
    unsigned xv = *(const unsigned*)(XR + (long)n * 64 + co);
    float x0 = __builtin_bit_cast(float, xv << 16);
    float x1 = __builtin_bit_cast(float, xv & 0xffff0000u);
    float r0 = a0 * inv + x0 + bias[co];
    float r1 = a1 * inv + x1 + bias[co + 1];
    *(float2*)(out + (long)n * 64 + co) = make_float2(r0, r1);
  }
}

// ---------------- launch ----------------

extern "C" void kernel_launch(void* const* d_in, const int* in_sizes, int n_in,
                              void* d_out, int out_size, void* d_ws, size_t ws_size,
                              hipStream_t stream) {
  const float* x   = (const float*)d_in[0];
  const int*   ei  = (const int*)d_in[1];
  const float* W1l = (const float*)d_in[2];
  const float* W1r = (const float*)d_in[3];
  const float* b1  = (const float*)d_in[4];
  const float* W2l = (const float*)d_in[5];
  const float* W2r = (const float*)d_in[6];
  const float* b2  = (const float*)d_in[7];
  float* out = (float*)d_out;

  int N = in_sizes[0] / K;   // 100000
  int E = in_sizes[1] / 2;   // 1600000
  const int* src = ei;
  const int* dst = ei + E;

  int nB = (N + 255) >> 8;          // 391 buckets
  int nblk = (E + EB - 1) / EB;     // 391 partition blocks

  char* ws = (char*)d_ws;
  size_t off = 0;
  auto alloc = [&](size_t bytes) {
    void* p = ws + off;
    off = (off + bytes + 255) & ~(size_t)255;
    return p;
  };
  int*      rowptr       = (int*)alloc(((size_t)N + 2) * 4);
  int*      col          = (int*)alloc((size_t)E * 4);
  int*      blockHist    = (int*)alloc((size_t)nblk * nB * 4);
  int*      bucketTotal  = (int*)alloc(((size_t)nB) * 4);
  int*      bucketBase   = (int*)alloc(((size_t)nB + 1) * 4);
  int*      bucketCursor = (int*)alloc((size_t)nB * 4);
  unsigned* recs         = (unsigned*)alloc((size_t)E * 4);
  unsigned char* y1      = (unsigned char*)alloc((size_t)N * 128);  // fp8
  __bf16*   xr           = (__bf16*)alloc((size_t)N * 128 * 2);
  __bf16*   h            = (__bf16*)alloc((size_t)N * 128 * 2);
  unsigned char* y2 = y1;  // layer-1 gather buffer dead after k_agg128; reuse
  __bf16*   hr = xr;

  // CSR build (bucketed)
  hipMemsetAsync(bucketTotal, 0, (size_t)nB * 4, stream);
  k_bhist<<<nblk, 256, nB * 4, stream>>>(dst, blockHist, bucketTotal, E, N, nB);
  k_btop<<<1, 512, 0, stream>>>(bucketTotal, bucketBase, bucketCursor, nB);
  k_bscatter<<<nblk, 256, nB * 4, stream>>>(src, dst, blockHist, bucketCursor, recs, E, N, nB);
  k_bfill<<<nB, 256, 0, stream>>>(recs, bucketBase, rowptr, col, N, nB);

  int gx = (N + 63) / 64;
  // layer 1: y1 = fp8(x@W1l), xr = bf16(x@W1r); h = relu(mean(y1) + xr + b1)
  k_gemm_mfma<128, float><<<dim3(gx, 2), 256, 0, stream>>>(x, W1l, W1r, y1, xr, N);
  k_agg128<true><<<(N + 3) / 4, 256, 0, stream>>>(y1, xr, b1, rowptr, col, h, N);

  // layer 2: y2 = fp8(h@W2l), hr = bf16(h@W2r); out = mean(y2) + hr + b2
  k_gemm_mfma<64, __bf16><<<dim3(gx, 2), 256, 0, stream>>>(h, W2l, W2r, y2, hr, N);
  k_agg64<<<(N + 3) / 4, 256, 0, stream>>>(y2, hr, b2, rowptr, col, out, N);
}

// Round 8
// 331.331 us; speedup vs baseline: 3.9838x; 1.0826x over previous
//
#include <hip/hip_runtime.h>
#include <type_traits>

// GraphSAGE 2-layer, N=100k, C 128->128->64, E=1.6M, fp32 in/out.
// R8: pre-transposed bf16 W (k_wprep) -> conflict-free GEMM B-staging
// (was 2.5e7 LDS bank conflicts from 16-way transposed ds_write_b16).
// fp8 gather buffers, bucketed CSR build, bf16-MFMA GEMMs.

constexpr int K = 128;
constexpr int EB = 4096;  // edges per partition block

typedef __bf16 bf16x2 __attribute__((ext_vector_type(2)));
typedef __bf16 bf16x4 __attribute__((ext_vector_type(4)));
typedef __bf16 bf16x8 __attribute__((ext_vector_type(8)));
typedef float f32x4 __attribute__((ext_vector_type(4)));
typedef float f32x2 __attribute__((ext_vector_type(2)));

// ---------------- fp8 e4m3 conversion ----------------

__device__ __forceinline__ unsigned char to_fp8(float v) {
#if __has_builtin(__builtin_amdgcn_cvt_pk_fp8_f32)
  int p = __builtin_amdgcn_cvt_pk_fp8_f32(v, v, 0, false);
  return (unsigned char)(p & 0xff);
#else
  unsigned u = __builtin_bit_cast(unsigned, v);
  unsigned s = (u >> 24) & 0x80u;
  float a = fabsf(v);
  if (a > 448.f) a = 448.f;
  unsigned bits;
  if (a < 0.015625f) {
    bits = (unsigned)(a * 512.f + 0.5f);
  } else {
    unsigned b = __builtin_bit_cast(unsigned, a);
    b += ((b >> 20) & 1) + 0x0007FFFF;
    unsigned e = (b >> 23) - 120;
    bits = (e << 3) | ((b >> 20) & 7);
    if (bits > 0x7E) bits = 0x7E;
  }
  return (unsigned char)(s | bits);
#endif
}

__device__ __forceinline__ f32x2 from_fp8x2(unsigned short u) {
#if __has_builtin(__builtin_amdgcn_cvt_pk_f32_fp8)
  return __builtin_amdgcn_cvt_pk_f32_fp8((int)u, false);
#else
  f32x2 r;
  unsigned b0 = u & 0xff, b1 = (u >> 8) & 0xff;
  unsigned e0 = (b0 >> 3) & 15, m0 = b0 & 7;
  unsigned e1 = (b1 >> 3) & 15, m1 = b1 & 7;
  float v0 = e0 ? __builtin_bit_cast(float, ((e0 + 120) << 23) | (m0 << 20))
              : (float)m0 * 0.001953125f;
  float v1 = e1 ? __builtin_bit_cast(float, ((e1 + 120) << 23) | (m1 << 20))
              : (float)m1 * 0.001953125f;
  r[0] = (b0 & 0x80) ? -v0 : v0;
  r[1] = (b1 & 0x80) ? -v1 : v1;
  return r;
#endif
}

// ---------------- W pre-transpose: fp32 [k][COLS] -> bf16 [c][128] ----------------

template <int COLS>
__global__ __launch_bounds__(256) void k_wprep(const float* __restrict__ W,
                                               __bf16* __restrict__ Bt) {
  int idx = blockIdx.x * 256 + threadIdx.x;  // coalesced read
  int k = idx / COLS, c = idx % COLS;
  Bt[c * K + k] = (__bf16)W[idx];  // small scattered 2B writes; L2-resident
}

// ---------------- bucketed CSR build ----------------

__global__ __launch_bounds__(256) void k_bhist(const int* __restrict__ dst,
                                               int* __restrict__ blockHist,
                                               int* __restrict__ bucketTotal,
                                               int E, int n, int nB) {
  extern __shared__ int hist[];
  for (int i = threadIdx.x; i < nB; i += 256) hist[i] = 0;
  __syncthreads();
  int base = blockIdx.x * EB, end = min(base + EB, E);
  for (int e = base + threadIdx.x; e < end; e += 256) {
    int d = dst[e];
    if ((unsigned)d < (unsigned)n) atomicAdd(&hist[d >> 8], 1);
  }
  __syncthreads();
  for (int i = threadIdx.x; i < nB; i += 256) {
    int v = hist[i];
    blockHist[(long)blockIdx.x * nB + i] = v;
    if (v) atomicAdd(&bucketTotal[i], v);
  }
}

__global__ __launch_bounds__(512) void k_btop(const int* __restrict__ bucketTotal,
                                              int* __restrict__ bucketBase,
                                              int* __restrict__ bucketCursor, int nB) {
  __shared__ int sh[512];
  int t = threadIdx.x;
  int s = (t < nB) ? bucketTotal[t] : 0;
  sh[t] = s;
  __syncthreads();
  for (int off = 1; off < 512; off <<= 1) {
    int v = (t >= off) ? sh[t - off] : 0;
    __syncthreads();
    sh[t] += v;
    __syncthreads();
  }
  if (t < nB) {
    int base = sh[t] - s;
    bucketBase[t] = base;
    bucketCursor[t] = base;
    if (t == nB - 1) bucketBase[nB] = sh[t];
  }
}

__global__ __launch_bounds__(256) void k_bscatter(const int* __restrict__ src,
                                                  const int* __restrict__ dst,
                                                  const int* __restrict__ blockHist,
                                                  int* __restrict__ bucketCursor,
                                                  unsigned* __restrict__ recs,
                                                  int E, int n, int nB) {
  extern __shared__ int cur[];
  for (int i = threadIdx.x; i < nB; i += 256) {
    int c = blockHist[(long)blockIdx.x * nB + i];
    cur[i] = c ? atomicAdd(&bucketCursor[i], c) : 0;
  }
  __syncthreads();
  int base = blockIdx.x * EB, end = min(base + EB, E);
  for (int e = base + threadIdx.x; e < end; e += 256) {
    int d = dst[e];
    if ((unsigned)d < (unsigned)n) {
      int s = min(max(src[e], 0), n - 1);
      int pos = atomicAdd(&cur[d >> 8], 1);
      recs[pos] = ((unsigned)s << 8) | (unsigned)(d & 255);
    }
  }
}

__global__ __launch_bounds__(256) void k_bfill(const unsigned* __restrict__ recs,
                                               const int* __restrict__ bucketBase,
                                               int* __restrict__ rowptr,
                                               int* __restrict__ col, int n, int nB) {
  __shared__ int degl[256];
  __shared__ int incl[256];
  int b = blockIdx.x, t = threadIdx.x;
  int rbeg = bucketBase[b], rend = bucketBase[b + 1];
  degl[t] = 0;
  __syncthreads();
  for (int i = rbeg + t; i < rend; i += 256)
    atomicAdd(&degl[recs[i] & 255], 1);
  __syncthreads();
  incl[t] = degl[t];
  __syncthreads();
  for (int off = 1; off < 256; off <<= 1) {
    int v = (t >= off) ? incl[t - off] : 0;
    __syncthreads();
    incl[t] += v;
    __syncthreads();
  }
  int excl = incl[t] - degl[t];
  int node = b * 256 + t;
  if (node <= n) rowptr[node] = rbeg + excl;
  __syncthreads();
  degl[t] = rbeg + excl;  // reuse as cursor
  __syncthreads();
  for (int i = rbeg + t; i < rend; i += 256) {
    unsigned r = recs[i];
    int pos = atomicAdd(&degl[r & 255], 1);
    col[pos] = (int)(r >> 8);
  }
}

// ---------------- bf16 MFMA GEMM ----------------
// out[64 x COLS] = X[64 x 128] @ W[128 x COLS]; B pre-transposed bf16 [c][k].
// blockIdx.y==0: outA (fp8, gather path); ==1: outB (bf16, self path).

template <int COLS, typename TIN>
__global__ __launch_bounds__(256) void k_gemm_mfma(const TIN* __restrict__ X,
                                                   const __bf16* __restrict__ Bta,
                                                   const __bf16* __restrict__ Btb,
                                                   unsigned char* __restrict__ outA,
                                                   __bf16* __restrict__ outB, int nrows) {
  constexpr int LD = 136;
  constexpr int MT_N = COLS / 32;
  __shared__ __bf16 sh[(64 + COLS) * LD];
  __bf16* As = sh;
  __bf16* Bt = sh + 64 * LD;

  bool isA = (blockIdx.y == 0);
  const __bf16* Btg = isA ? Bta : Btb;

  int tid = threadIdx.x;
  long row0 = (long)blockIdx.x * 64;

  // stage A (convert to bf16 if fp32 input)
  if constexpr (std::is_same_v<TIN, float>) {
#pragma unroll
    for (int it = 0; it < 8; ++it) {
      int i = tid + it * 256;
      int r = i >> 5, c4 = (i & 31) << 2;
      long row = row0 + r;
      float4 v = make_float4(0.f, 0.f, 0.f, 0.f);
      if (row < nrows) v = *(const float4*)(X + row * K + c4);
      bf16x4 bb;
      bb[0] = (__bf16)v.x; bb[1] = (__bf16)v.y; bb[2] = (__bf16)v.z; bb[3] = (__bf16)v.w;
      *(bf16x4*)&As[r * LD + c4] = bb;
    }
  } else {
#pragma unroll
    for (int it = 0; it < 4; ++it) {
      int i = tid + it * 256;
      int r = i >> 4, c8 = (i & 15) << 3;
      long row = row0 + r;
      bf16x8 v = {};
      if (row < nrows) v = *(const bf16x8*)(X + row * K + c8);
      *(bf16x8*)&As[r * LD + c8] = v;
    }
  }
  // stage B: contiguous bf16x8 copies (conflict-free; 16 lanes = one 256B row)
#pragma unroll
  for (int it = 0; it < (COLS * 16) / 256; ++it) {
    int i = tid + it * 256;
    int c = i >> 4, kk = (i & 15) << 3;
    *(bf16x8*)&Bt[c * LD + kk] = *(const bf16x8*)(Btg + c * K + kk);
  }
  __syncthreads();

  int w = tid >> 6, lane = tid & 63;
  int m = lane & 15, quad = lane >> 4;
  int wrow = (w >> 1) * 32;
  int wcol = (w & 1) * (COLS / 2);

  f32x4 acc[2][MT_N];
#pragma unroll
  for (int mi = 0; mi < 2; ++mi)
#pragma unroll
    for (int ni = 0; ni < MT_N; ++ni) acc[mi][ni] = (f32x4){0.f, 0.f, 0.f, 0.f};

#pragma unroll
  for (int kc = 0; kc < 4; ++kc) {
    int ko = kc * 32 + quad * 8;
    bf16x8 af[2];
#pragma unroll
    for (int mi = 0; mi < 2; ++mi)
      af[mi] = *(const bf16x8*)&As[(wrow + mi * 16 + m) * LD + ko];
    bf16x8 bfr[MT_N];
#pragma unroll
    for (int ni = 0; ni < MT_N; ++ni)
      bfr[ni] = *(const bf16x8*)&Bt[(wcol + ni * 16 + m) * LD + ko];
#pragma unroll
    for (int mi = 0; mi < 2; ++mi)
#pragma unroll
      for (int ni = 0; ni < MT_N; ++ni)
        acc[mi][ni] = __builtin_amdgcn_mfma_f32_16x16x32_bf16(af[mi], bfr[ni], acc[mi][ni], 0, 0, 0);
  }

#pragma unroll
  for (int mi = 0; mi < 2; ++mi) {
#pragma unroll
    for (int r = 0; r < 4; ++r) {
      long grow = row0 + wrow + mi * 16 + quad * 4 + r;
      if (grow < nrows) {
#pragma unroll
        for (int ni = 0; ni < MT_N; ++ni) {
          long idx = grow * COLS + wcol + ni * 16 + m;
          float v = acc[mi][ni][r];
          if (isA) outA[idx] = to_fp8(v);
          else     outB[idx] = (__bf16)v;
        }
      }
    }
  }
}

// ---------------- aggregation ----------------

template <bool RELU>
__global__ __launch_bounds__(256) void k_agg128(const unsigned char* __restrict__ Y,
                                                const __bf16* __restrict__ XR,
                                                const float* __restrict__ bias,
                                                const int* __restrict__ rowptr,
                                                const int* __restrict__ col,
                                                __bf16* __restrict__ out, int nnodes) {
  int wave = threadIdx.x >> 6, lane = threadIdx.x & 63;
  int n = blockIdx.x * 4 + wave;
  if (n >= nnodes) return;
  int beg = rowptr[n], end = rowptr[n + 1];
  float inv = 1.f / (float)max(end - beg, 1);
  int co = lane * 2;

  float a0 = 0.f, a1 = 0.f;
  int j = beg;
  for (; j + 3 < end; j += 4) {
    long s0 = col[j], s1 = col[j + 1], s2 = col[j + 2], s3 = col[j + 3];
    unsigned short v0 = *(const unsigned short*)(Y + s0 * 128 + co);
    unsigned short v1 = *(const unsigned short*)(Y + s1 * 128 + co);
    unsigned short v2 = *(const unsigned short*)(Y + s2 * 128 + co);
    unsigned short v3 = *(const unsigned short*)(Y + s3 * 128 + co);
    f32x2 f0 = from_fp8x2(v0), f1 = from_fp8x2(v1);
    f32x2 f2 = from_fp8x2(v2), f3 = from_fp8x2(v3);
    a0 += f0[0] + f1[0] + f2[0] + f3[0];
    a1 += f0[1] + f1[1] + f2[1] + f3[1];
  }
  for (; j < end; ++j) {
    long s = col[j];
    f32x2 f = from_fp8x2(*(const unsigned short*)(Y + s * 128 + co));
    a0 += f[0];
    a1 += f[1];
  }
  unsigned xv = *(const unsigned*)(XR + (long)n * 128 + co);
  float x0 = __builtin_bit_cast(float, xv << 16);
  float x1 = __builtin_bit_cast(float, xv & 0xffff0000u);
  float r0 = a0 * inv + x0 + bias[co];
  float r1 = a1 * inv + x1 + bias[co + 1];
  if (RELU) { r0 = fmaxf(r0, 0.f); r1 = fmaxf(r1, 0.f); }
  bf16x2 o;
  o[0] = (__bf16)r0; o[1] = (__bf16)r1;
  *(bf16x2*)(out + (long)n * 128 + co) = o;
}

__global__ __launch_bounds__(256) void k_agg64(const unsigned char* __restrict__ Y,
                                               const __bf16* __restrict__ XR,
                                               const float* __restrict__ bias,
                                               const int* __restrict__ rowptr,
                                               const int* __restrict__ col,
                                               float* __restrict__ out, int nnodes) {
  int wave = threadIdx.x >> 6, lane = threadIdx.x & 63;
  int n = blockIdx.x * 4 + wave;
  if (n >= nnodes) return;
  int beg = rowptr[n], end = rowptr[n + 1];
  int half = lane >> 5;
  int l = lane & 31;
  int co = l * 2;

  float a0 = 0.f, a1 = 0.f;
  int j = beg;
  for (; j + 7 < end; j += 8) {
    long s0 = col[j + half], s1 = col[j + 2 + half];
    long s2 = col[j + 4 + half], s3 = col[j + 6 + half];
    f32x2 f0 = from_fp8x2(*(const unsigned short*)(Y + s0 * 64 + co));
    f32x2 f1 = from_fp8x2(*(const unsigned short*)(Y + s1 * 64 + co));
    f32x2 f2 = from_fp8x2(*(const unsigned short*)(Y + s2 * 64 + co));
    f32x2 f3 = from_fp8x2(*(const unsigned short*)(Y + s3 * 64 + co));
    a0 += f0[0] + f1[0] + f2[0] + f3[0];
    a1 += f0[1] + f1[1] + f2[1] + f3[1];
  }
  for (; j + 1 < end; j += 2) {
    long s = col[j + half];
    f32x2 f = from_fp8x2(*(const unsigned short*)(Y + s * 64 + co));
    a0 += f[0];
    a1 += f[1];
  }
  if (j < end && half == 0) {
    long s = col[j];
    f32x2 f = from_fp8x2(*(const unsigned short*)(Y + s * 64 + co));
    a0 += f[0];
    a1 += f[1];
  }
  a0 += __shfl_down(a0, 32);
  a1 += __shfl_down(a1, 32);
  if (half == 0) {
    float inv = 1.f / (float)max(end - beg, 1);
    unsigned xv = *(const unsigned*)(XR + (long)n * 64 + co);
    float x0 = __builtin_bit_cast(float, xv << 16);
    float x1 = __builtin_bit_cast(float, xv & 0xffff0000u);
    float r0 = a0 * inv + x0 + bias[co];
    float r1 = a1 * inv + x1 + bias[co + 1];
    *(float2*)(out + (long)n * 64 + co) = make_float2(r0, r1);
  }
}

// ---------------- launch ----------------

extern "C" void kernel_launch(void* const* d_in, const int* in_sizes, int n_in,
                              void* d_out, int out_size, void* d_ws, size_t ws_size,
                              hipStream_t stream) {
  const float* x   = (const float*)d_in[0];
  const int*   ei  = (const int*)d_in[1];
  const float* W1l = (const float*)d_in[2];
  const float* W1r = (const float*)d_in[3];
  const float* b1  = (const float*)d_in[4];
  const float* W2l = (const float*)d_in[5];
  const float* W2r = (const float*)d_in[6];
  const float* b2  = (const float*)d_in[7];
  float* out = (float*)d_out;

  int N = in_sizes[0] / K;   // 100000
  int E = in_sizes[1] / 2;   // 1600000
  const int* src = ei;
  const int* dst = ei + E;

  int nB = (N + 255) >> 8;          // 391 buckets
  int nblk = (E + EB - 1) / EB;     // 391 partition blocks

  char* ws = (char*)d_ws;
  size_t off = 0;
  auto alloc = [&](size_t bytes) {
    void* p = ws + off;
    off = (off + bytes + 255) & ~(size_t)255;
    return p;
  };
  int*      rowptr       = (int*)alloc(((size_t)N + 2) * 4);
  int*      col          = (int*)alloc((size_t)E * 4);
  int*      blockHist    = (int*)alloc((size_t)nblk * nB * 4);
  int*      bucketTotal  = (int*)alloc(((size_t)nB) * 4);
  int*      bucketBase   = (int*)alloc(((size_t)nB + 1) * 4);
  int*      bucketCursor = (int*)alloc((size_t)nB * 4);
  unsigned* recs         = (unsigned*)alloc((size_t)E * 4);
  unsigned char* y1      = (unsigned char*)alloc((size_t)N * 128);  // fp8
  __bf16*   xr           = (__bf16*)alloc((size_t)N * 128 * 2);
  __bf16*   h            = (__bf16*)alloc((size_t)N * 128 * 2);
  __bf16*   Bt1l         = (__bf16*)alloc((size_t)128 * K * 2);
  __bf16*   Bt1r         = (__bf16*)alloc((size_t)128 * K * 2);
  __bf16*   Bt2l         = (__bf16*)alloc((size_t)64 * K * 2);
  __bf16*   Bt2r         = (__bf16*)alloc((size_t)64 * K * 2);
  unsigned char* y2 = y1;  // layer-1 gather buffer dead after k_agg128; reuse
  __bf16*   hr = xr;

  // W pre-transpose (independent of CSR build)
  k_wprep<128><<<(K * 128) / 256, 256, 0, stream>>>(W1l, Bt1l);
  k_wprep<128><<<(K * 128) / 256, 256, 0, stream>>>(W1r, Bt1r);
  k_wprep<64><<<(K * 64) / 256, 256, 0, stream>>>(W2l, Bt2l);
  k_wprep<64><<<(K * 64) / 256, 256, 0, stream>>>(W2r, Bt2r);

  // CSR build (bucketed)
  hipMemsetAsync(bucketTotal, 0, (size_t)nB * 4, stream);
  k_bhist<<<nblk, 256, nB * 4, stream>>>(dst, blockHist, bucketTotal, E, N, nB);
  k_btop<<<1, 512, 0, stream>>>(bucketTotal, bucketBase, bucketCursor, nB);
  k_bscatter<<<nblk, 256, nB * 4, stream>>>(src, dst, blockHist, bucketCursor, recs, E, N, nB);
  k_bfill<<<nB, 256, 0, stream>>>(recs, bucketBase, rowptr, col, N, nB);

  int gx = (N + 63) / 64;
  // layer 1: y1 = fp8(x@W1l), xr = bf16(x@W1r); h = relu(mean(y1) + xr + b1)
  k_gemm_mfma<128, float><<<dim3(gx, 2), 256, 0, stream>>>(x, Bt1l, Bt1r, y1, xr, N);
  k_agg128<true><<<(N + 3) / 4, 256, 0, stream>>>(y1, xr, b1, rowptr, col, h, N);

  // layer 2: y2 = fp8(h@W2l), hr = bf16(h@W2r); out = mean(y2) + hr + b2
  k_gemm_mfma<64, __bf16><<<dim3(gx, 2), 256, 0, stream>>>(h, Bt2l, Bt2r, y2, hr, N);
  k_agg64<<<(N + 3) / 4, 256, 0, stream>>>(y2, hr, b2, rowptr, col, out, N);
}